// Round 7
// baseline (14917.319 us; speedup 1.0000x reference)
//
#include <hip/hip_runtime.h>

// SNN: v_dec = v + 0.1*(i - v); i_dec = 0.8*i; spike if v_dec > 1.0
// v' = spike ? 0 : v_dec; i' = i_dec + input.
// Whole-sequence kernels: LIF state lives in registers across the t-loop.

#define T_STEPS 32

// Bijective XCD-chunked block swizzle (m204): XCD k gets a contiguous wgid range.
__device__ __forceinline__ int xcd_swz(int orig, int nwg) {
    const int q = nwg >> 3, r = nwg & 7;
    const int xcd = orig & 7, idx = orig >> 3;
    return (xcd < r ? xcd * (q + 1) : r * (q + 1) + (xcd - r) * q) + idx;
}

// ---------------- K0: transpose x [t][b][64][64] -> xT [t][y][x][b] ----------------
__global__ __launch_bounds__(256) void k_tr(
    const float* __restrict__ x, float* __restrict__ xT)
{
    const int y = blockIdx.x, t = blockIdx.y;
    const int tid = threadIdx.x;
    __shared__ float tile[32][65];

    const int lx = tid & 63, bg = tid >> 6;
    #pragma unroll
    for (int p = 0; p < 8; ++p) {
        const int b = bg + p * 4;
        tile[b][lx] = x[((size_t)(t * 32 + b) * 64 + y) * 64 + lx];
    }
    __syncthreads();
    const int wb = tid & 31, xg = tid >> 5;
    #pragma unroll
    for (int p = 0; p < 8; ++p) {
        const int xx = xg + p * 8;
        xT[((size_t)(t * 64 + y) * 64 + xx) * 32 + wb] = tile[wb][xx];
    }
}

// load 6x6 window (stride 'rs' floats per row, 32 floats per col) into 36 regs
#define LOADWIN(dst, pbase, rs)                                          \
    do {                                                                 \
        _Pragma("unroll")                                                \
        for (int _r = 0; _r < 6; ++_r) {                                 \
            const float* __restrict__ _pr = (pbase) + _r * (rs);         \
            _Pragma("unroll")                                            \
            for (int _c = 0; _c < 6; ++_c)                               \
                dst[_r * 6 + _c] = _pr[_c * 32];                         \
        }                                                                \
    } while (0)

// 25-tap FMA over a 6x6 window for 2x2 outputs
#define FMA25(xr, wp, acc)                                               \
    do {                                                                 \
        _Pragma("unroll")                                                \
        for (int _ky = 0; _ky < 5; ++_ky) {                              \
            _Pragma("unroll")                                            \
            for (int _kx = 0; _kx < 5; ++_kx) {                          \
                const float _w = (wp)[_ky * 5 + _kx];                    \
                acc[0] = fmaf(_w, xr[_ky * 6 + _kx],           acc[0]);  \
                acc[1] = fmaf(_w, xr[_ky * 6 + _kx + 1],       acc[1]);  \
                acc[2] = fmaf(_w, xr[(_ky + 1) * 6 + _kx],     acc[2]);  \
                acc[3] = fmaf(_w, xr[(_ky + 1) * 6 + _kx + 1], acc[3]);  \
            }                                                            \
        }                                                                \
    } while (0)

// ---------------- K1: conv1 (1->16) + LIF + pool, ALL timesteps ----------------
// grid 900 (XCD-swizzled), block 256 = 32 b x 8 slots (2 co per slot).
// Cross-t register double-buffer: window for t+1 prefetched during t's FMAs.
__global__ __launch_bounds__(256) void k1_conv1(
    const float* __restrict__ xT,    // [32t,64,64,32b]
    const float* __restrict__ w1,    // [16,1,5,5]
    const float* __restrict__ b1,    // [16]
    float* __restrict__ zp1a)        // [32t][16,30,30,32b]
{
    const int pos = xcd_swz(blockIdx.x, 900);
    const int py = pos / 30, px = pos % 30;
    const int y0 = 2 * py, x0 = 2 * px;
    const int tid = threadIdx.x;
    const int b = tid & 31, slot = tid >> 5;

    __shared__ float ws[400];
    for (int i = tid; i < 400; i += 256) ws[i] = w1[i];
    __syncthreads();
    const float bias0 = b1[slot], bias1 = b1[slot + 8];
    const float* __restrict__ base = xT + ((size_t)(y0 * 64 + x0)) * 32 + b;

    float v[2][4] = {{0.f,0.f,0.f,0.f},{0.f,0.f,0.f,0.f}};
    float cu[2][4] = {{0.f,0.f,0.f,0.f},{0.f,0.f,0.f,0.f}};
    float xrA[36], xrB[36];

    LOADWIN(xrA, base, 2048);  // t=0

    for (int tp = 0; tp < 16; ++tp) {
        const int t0 = 2 * tp, t1 = 2 * tp + 1;
        // prefetch t1 while computing t0
        LOADWIN(xrB, base + (size_t)t1 * 131072, 2048);
        #pragma unroll
        for (int half = 0; half < 2; ++half) {
            const int co = slot + 8 * half;
            float acc[4] = {0.f, 0.f, 0.f, 0.f};
            FMA25(xrA, ws + co * 25, acc);
            const float bias = half ? bias1 : bias0;
            float zmax = 0.f;
            #pragma unroll
            for (int q = 0; q < 4; ++q) {
                const float inp = acc[q] + bias;
                const float vv = v[half][q], cur = cu[half][q];
                const float vd = vv + 0.1f * (cur - vv);
                const float id = 0.8f * cur;
                const float z = (vd - 1.0f > 0.0f) ? 1.0f : 0.0f;
                v[half][q] = (z > 0.f) ? 0.f : vd;
                cu[half][q] = id + inp;
                zmax = fmaxf(zmax, z);
            }
            zp1a[(size_t)t0 * 460800 + ((co * 30 + py) * 30 + px) * 32 + b] = zmax;
        }
        // prefetch t0+2 while computing t1
        if (tp < 15) LOADWIN(xrA, base + (size_t)(t0 + 2) * 131072, 2048);
        #pragma unroll
        for (int half = 0; half < 2; ++half) {
            const int co = slot + 8 * half;
            float acc[4] = {0.f, 0.f, 0.f, 0.f};
            FMA25(xrB, ws + co * 25, acc);
            const float bias = half ? bias1 : bias0;
            float zmax = 0.f;
            #pragma unroll
            for (int q = 0; q < 4; ++q) {
                const float inp = acc[q] + bias;
                const float vv = v[half][q], cur = cu[half][q];
                const float vd = vv + 0.1f * (cur - vv);
                const float id = 0.8f * cur;
                const float z = (vd - 1.0f > 0.0f) ? 1.0f : 0.0f;
                v[half][q] = (z > 0.f) ? 0.f : vd;
                cu[half][q] = id + inp;
                zmax = fmaxf(zmax, z);
            }
            zp1a[(size_t)t1 * 460800 + ((co * 30 + py) * 30 + px) * 32 + b] = zmax;
        }
    }
}

// ---------------- K2: conv2 (16->32)*10 + LIF + pool, ALL timesteps ----------------
// grid 676 (XCD-swizzled, co-group minor), block 256 = 32 b x 8 slots.
// Register double-buffer across ci: loads for ci+1 in flight during ci's FMAs;
// last ci prefetches t+1's ci=0 (pipeline never drains).
__global__ __launch_bounds__(256) void k2_conv2(
    const float* __restrict__ zp1a,  // [32t][16,30,30,32b]
    const float* __restrict__ w2,    // [32,16,5,5]
    const float* __restrict__ b2,    // [32]
    float* __restrict__ zp2a)        // [32t][5408,32b]
{
    const int wgid = xcd_swz(blockIdx.x, 676);
    const int pos = wgid >> 2;
    const int cob = (wgid & 3) * 8;
    const int py = pos / 13, px = pos % 13;
    const int y0 = 2 * py, x0 = 2 * px;
    const int tid = threadIdx.x;
    const int b = tid & 31, slot = tid >> 5;

    __shared__ float ws[3584];  // [8co][16ci][28 padded]
    __shared__ float bs[8];
    for (int i = tid; i < 3200; i += 256) {
        const int co_l = i / 400;
        const int rest = i - co_l * 400;
        const int ci = rest / 25;
        const int j = rest - ci * 25;
        ws[(co_l * 16 + ci) * 28 + j] = w2[cob * 400 + i];
    }
    if (tid < 8) bs[tid] = b2[cob + tid];
    __syncthreads();

    const int co = cob + slot;
    const float bias = bs[slot];
    const float* __restrict__ wsl = ws + slot * 448;  // + ci*28
    const float* __restrict__ base = zp1a + ((size_t)(y0 * 30 + x0)) * 32 + b;

    float v[4] = {0.f,0.f,0.f,0.f};
    float cu[4] = {0.f,0.f,0.f,0.f};
    float xrA[36], xrB[36];

    LOADWIN(xrA, base, 960);  // t=0, ci=0

    for (int t = 0; t < T_STEPS; ++t) {
        const float* __restrict__ bt = base + (size_t)t * 460800;
        float acc[4] = {0.f, 0.f, 0.f, 0.f};

        #pragma unroll
        for (int cp = 0; cp < 8; ++cp) {
            LOADWIN(xrB, bt + (2 * cp + 1) * 28800, 960);
            FMA25(xrA, wsl + (2 * cp) * 28, acc);
            if (cp < 7) {
                LOADWIN(xrA, bt + (2 * cp + 2) * 28800, 960);
            } else if (t < T_STEPS - 1) {
                LOADWIN(xrA, bt + 460800, 960);  // t+1, ci=0
            }
            FMA25(xrB, wsl + (2 * cp + 1) * 28, acc);
        }

        float zmax = 0.f;
        #pragma unroll
        for (int q = 0; q < 4; ++q) {
            const float inp = 10.f * (acc[q] + bias);
            const float vv = v[q], cur = cu[q];
            const float vd = vv + 0.1f * (cur - vv);
            const float id = 0.8f * cur;
            const float z = (vd - 1.0f > 0.0f) ? 1.0f : 0.0f;
            v[q] = (z > 0.f) ? 0.f : vd;
            cu[q] = id + inp;
            zmax = fmaxf(zmax, z);
        }
        zp2a[(size_t)t * 173056 + (co * 169 + pos) * 32 + b] = zmax;
    }
}

// ---------------- K3: FC as LDS-tiled GEMM ----------------
__global__ __launch_bounds__(256) void k3_gemm(
    const float* __restrict__ zp2a,  // [32t][5408][32b]
    const float* __restrict__ fw,    // [500,5408]
    float* __restrict__ part)        // [8kc][512n][1024col]
{
    const int nt = blockIdx.x, mt = blockIdx.y, kc = blockIdx.z;
    const int tid = threadIdx.x;
    const int cx = tid & 31, ry = tid >> 5;
    const int c0 = nt * 128, m0 = mt * 64, k0 = kc * 676;

    __shared__ float A[26][64];    // [k][n]
    __shared__ float Bs[26][128];  // [k][col]

    float acc[8][4] = {};

    for (int ks = 0; ks < 26; ++ks) {
        const int kb = k0 + ks * 26;
        __syncthreads();
        for (int i = tid; i < 1664; i += 256) {
            const int row = i / 26, kk = i - row * 26;
            int n = m0 + row; if (n > 499) n = 499;
            A[kk][row] = fw[n * 5408 + kb + kk];
        }
        for (int i = tid; i < 3328; i += 256) {
            const int kk = i >> 7, c = i & 127;
            const int col = c0 + c;
            Bs[kk][c] = zp2a[(size_t)(col >> 5) * 173056 + (kb + kk) * 32 + (col & 31)];
        }
        __syncthreads();

        for (int kk = 0; kk < 26; ++kk) {
            const float4 b4 = *(const float4*)&Bs[kk][cx * 4];
            const float4 a0 = *(const float4*)&A[kk][ry * 8];
            const float4 a1 = *(const float4*)&A[kk][ry * 8 + 4];
            const float av[8] = {a0.x, a0.y, a0.z, a0.w, a1.x, a1.y, a1.z, a1.w};
            const float bv[4] = {b4.x, b4.y, b4.z, b4.w};
            #pragma unroll
            for (int i2 = 0; i2 < 8; ++i2)
                #pragma unroll
                for (int j = 0; j < 4; ++j)
                    acc[i2][j] = fmaf(av[i2], bv[j], acc[i2][j]);
        }
    }

    float* pp = part + ((size_t)kc * 512 + m0) * 1024 + c0;
    #pragma unroll
    for (int i2 = 0; i2 < 8; ++i2) {
        const int row = ry * 8 + i2;
        float4 o; o.x = acc[i2][0]; o.y = acc[i2][1]; o.z = acc[i2][2]; o.w = acc[i2][3];
        *(float4*)&pp[row * 1024 + cx * 4] = o;
    }
}

// ---------------- K3b: reduce partials + bias + LIF scan over t ----------------
__global__ __launch_bounds__(256) void k3b_lif(
    const float* __restrict__ part,  // [8kc][512n][1024col], col = t*32+b
    const float* __restrict__ fb,    // [500]
    float* __restrict__ za)          // [32t][500][32]
{
    const int idx = blockIdx.x * 256 + threadIdx.x;
    if (idx >= 16000) return;
    const int n = idx >> 5, b = idx & 31;
    const float bias = fb[n];

    float v = 0.f, cu = 0.f;
    for (int t = 0; t < T_STEPS; ++t) {
        float s = 0.f;
        #pragma unroll
        for (int p = 0; p < 8; ++p)
            s += part[(size_t)p * 524288 + n * 1024 + t * 32 + b];
        s += bias;

        const float vd = v + 0.1f * (cu - v);
        const float id = 0.8f * cu;
        const float z = (vd - 1.0f > 0.0f) ? 1.0f : 0.0f;
        v = (z > 0.f) ? 0.f : vd;
        cu = id + s;
        za[(size_t)t * 16000 + idx] = z;
    }
}

// ---------------- K4: readout dots per (c,t) ----------------
__global__ __launch_bounds__(256) void k4_dot(
    const float* __restrict__ za,   // [32t][500][32]
    const float* __restrict__ ow,   // [10,500]
    float* __restrict__ dota)       // [32t][10][32]
{
    const int c = blockIdx.x, t = blockIdx.y;
    const int tid = threadIdx.x;
    const int b = tid & 31, nc = tid >> 5;
    const float* __restrict__ wr = ow + c * 500;
    const float* __restrict__ zt = za + (size_t)t * 16000;

    float acc = 0.f;
    for (int j = 0; j < 63; ++j) {
        const int n = nc * 63 + j;
        if (n < 500) acc = fmaf(zt[n * 32 + b], wr[n], acc);
    }

    __shared__ float red[256];
    red[tid] = acc;
    __syncthreads();
    if (tid < 32) {
        float dot = 0.f;
        #pragma unroll
        for (int q = 0; q < 8; ++q) dot += red[q * 32 + tid];
        dota[((size_t)t * 10 + c) * 32 + tid] = dot;
    }
}

// ---------------- K5: LI scan + output ----------------
__global__ __launch_bounds__(320) void k5_li(
    const float* __restrict__ dota,  // [32t][10][32]
    float* __restrict__ outp)        // [32t][32b][10c]
{
    const int tid = threadIdx.x;
    if (tid >= 320) return;
    const int c = tid / 32, b = tid & 31;

    float vo = 0.f, io = 0.f;
    for (int t = 0; t < T_STEPS; ++t) {
        const float vout = vo + 0.1f * (io - vo);
        outp[t * 320 + b * 10 + c] = vout;
        vo = vout;
        io = 0.8f * io + dota[(t * 10 + c) * 32 + b];
    }
}

extern "C" void kernel_launch(void* const* d_in, const int* in_sizes, int n_in,
                              void* d_out, int out_size, void* d_ws, size_t ws_size,
                              hipStream_t stream) {
    const float* x  = (const float*)d_in[0];  // [32,32,1,64,64]
    const float* w1 = (const float*)d_in[1];
    const float* b1 = (const float*)d_in[2];
    const float* w2 = (const float*)d_in[3];
    const float* b2 = (const float*)d_in[4];
    const float* fw = (const float*)d_in[5];
    const float* fb = (const float*)d_in[6];
    const float* ow = (const float*)d_in[7];
    float* out = (float*)d_out;
    float* ws = (float*)d_ws;

    size_t off = 0;
    float* xT   = ws + off; off += 4194304;   // [32t][64][64][32b]; dead after k1
    float* zp1a = ws + off; off += 14745600;  // [32t][16*30*30][32b]
    float* zp2a = ws + off; off += 5537792;   // [32t][5408][32b]
    float* za   = ws + off; off += 512000;    // [32t][500][32b]
    float* dota = ws + off; off += 10240;     // [32t][10][32b]
    float* part = xT;                         // alias: [8][512][1024] = 4194304 floats
    // ~100 MB total; every buffer fully written before read (no memset needed).

    k_tr    <<<dim3(64, 32), 256, 0, stream>>>(x, xT);
    k1_conv1<<<900, 256, 0, stream>>>(xT, w1, b1, zp1a);
    k2_conv2<<<676, 256, 0, stream>>>(zp1a, w2, b2, zp2a);
    k3_gemm <<<dim3(8, 8, 8), 256, 0, stream>>>(zp2a, fw, part);
    k3b_lif <<<63, 256, 0, stream>>>(part, fb, za);
    k4_dot  <<<dim3(10, 32), 256, 0, stream>>>(za, ow, dota);
    k5_li   <<<1, 320, 0, stream>>>(dota, out);
}

// Round 8
// 978.062 us; speedup vs baseline: 15.2519x; 15.2519x over previous
//
#include <hip/hip_runtime.h>

// SNN: v_dec = v + 0.1*(i - v); i_dec = 0.8*i; spike if v_dec > 1.0
// v' = spike ? 0 : v_dec; i' = i_dec + input.
// Whole-sequence kernels: LIF state lives in registers across the t-loop.

#define T_STEPS 32

// Bijective XCD-chunked block swizzle (m204): XCD k gets a contiguous wgid range.
__device__ __forceinline__ int xcd_swz(int orig, int nwg) {
    const int q = nwg >> 3, r = nwg & 7;
    const int xcd = orig & 7, idx = orig >> 3;
    return (xcd < r ? xcd * (q + 1) : r * (q + 1) + (xcd - r) * q) + idx;
}

// ---------------- K0: transpose x [t][b][64][64] -> xT [t][y][x][b] ----------------
__global__ __launch_bounds__(256) void k_tr(
    const float* __restrict__ x, float* __restrict__ xT)
{
    const int y = blockIdx.x, t = blockIdx.y;
    const int tid = threadIdx.x;
    __shared__ float tile[32][65];

    const int lx = tid & 63, bg = tid >> 6;
    #pragma unroll
    for (int p = 0; p < 8; ++p) {
        const int b = bg + p * 4;
        tile[b][lx] = x[((size_t)(t * 32 + b) * 64 + y) * 64 + lx];
    }
    __syncthreads();
    const int wb = tid & 31, xg = tid >> 5;
    #pragma unroll
    for (int p = 0; p < 8; ++p) {
        const int xx = xg + p * 8;
        xT[((size_t)(t * 64 + y) * 64 + xx) * 32 + wb] = tile[wb][xx];
    }
}

// load 6x6 window (stride 'rs' floats per row, 32 floats per col) into 36 regs
#define LOADWIN(dst, pbase, rs)                                          \
    do {                                                                 \
        _Pragma("unroll")                                                \
        for (int _r = 0; _r < 6; ++_r) {                                 \
            const float* __restrict__ _pr = (pbase) + _r * (rs);         \
            _Pragma("unroll")                                            \
            for (int _c = 0; _c < 6; ++_c)                               \
                dst[_r * 6 + _c] = _pr[_c * 32];                         \
        }                                                                \
    } while (0)

// 25-tap FMA over a 6x6 window for 2x2 outputs
#define FMA25(xr, wp, acc)                                               \
    do {                                                                 \
        _Pragma("unroll")                                                \
        for (int _ky = 0; _ky < 5; ++_ky) {                              \
            _Pragma("unroll")                                            \
            for (int _kx = 0; _kx < 5; ++_kx) {                          \
                const float _w = (wp)[_ky * 5 + _kx];                    \
                acc[0] = fmaf(_w, xr[_ky * 6 + _kx],           acc[0]);  \
                acc[1] = fmaf(_w, xr[_ky * 6 + _kx + 1],       acc[1]);  \
                acc[2] = fmaf(_w, xr[(_ky + 1) * 6 + _kx],     acc[2]);  \
                acc[3] = fmaf(_w, xr[(_ky + 1) * 6 + _kx + 1], acc[3]);  \
            }                                                            \
        }                                                                \
    } while (0)

// ---------------- K1: conv1 (1->16) + LIF + pool, ALL timesteps ----------------
// grid 900 (XCD-swizzled), block 256 = 32 b x 8 slots (2 co per slot).
// (round-6 form: no pipeline — k1 is not the bottleneck)
__global__ __launch_bounds__(256) void k1_conv1(
    const float* __restrict__ xT,    // [32t,64,64,32b]
    const float* __restrict__ w1,    // [16,1,5,5]
    const float* __restrict__ b1,    // [16]
    float* __restrict__ zp1a)        // [32t][16,30,30,32b]
{
    const int pos = xcd_swz(blockIdx.x, 900);
    const int py = pos / 30, px = pos % 30;
    const int y0 = 2 * py, x0 = 2 * px;
    const int tid = threadIdx.x;
    const int b = tid & 31, slot = tid >> 5;

    __shared__ float ws[400];
    for (int i = tid; i < 400; i += 256) ws[i] = w1[i];
    __syncthreads();
    const float bias0 = b1[slot], bias1 = b1[slot + 8];

    float v[2][4] = {{0.f,0.f,0.f,0.f},{0.f,0.f,0.f,0.f}};
    float cu[2][4] = {{0.f,0.f,0.f,0.f},{0.f,0.f,0.f,0.f}};

    for (int t = 0; t < T_STEPS; ++t) {
        float xr[36];
        const float* __restrict__ bt =
            xT + ((size_t)(t * 64 + y0) * 64 + x0) * 32 + b;
        LOADWIN(xr, bt, 2048);

        #pragma unroll
        for (int half = 0; half < 2; ++half) {
            const int co = slot + 8 * half;
            float acc[4] = {0.f, 0.f, 0.f, 0.f};
            FMA25(xr, ws + co * 25, acc);
            const float bias = half ? bias1 : bias0;
            float zmax = 0.f;
            #pragma unroll
            for (int q = 0; q < 4; ++q) {
                const float inp = acc[q] + bias;
                const float vv = v[half][q], cur = cu[half][q];
                const float vd = vv + 0.1f * (cur - vv);
                const float id = 0.8f * cur;
                const float z = (vd - 1.0f > 0.0f) ? 1.0f : 0.0f;
                v[half][q] = (z > 0.f) ? 0.f : vd;
                cu[half][q] = id + inp;
                zmax = fmaxf(zmax, z);
            }
            zp1a[(size_t)t * 460800 + ((co * 30 + py) * 30 + px) * 32 + b] = zmax;
        }
    }
}

// ---------------- K2: conv2 (16->32)*10 + LIF + pool, ALL timesteps ----------------
// grid 676 (XCD-swizzled, co-group minor), block 256 = 32 b x 8 slots.
// 2-stage register double-buffer across ci with BOUNDED liveness:
// `#pragma unroll 1` keeps exactly one loop body (72 window regs live).
__global__ __launch_bounds__(256) void k2_conv2(
    const float* __restrict__ zp1a,  // [32t][16,30,30,32b]
    const float* __restrict__ w2,    // [32,16,5,5]
    const float* __restrict__ b2,    // [32]
    float* __restrict__ zp2a)        // [32t][5408,32b]
{
    const int wgid = xcd_swz(blockIdx.x, 676);
    const int pos = wgid >> 2;
    const int cob = (wgid & 3) * 8;
    const int py = pos / 13, px = pos % 13;
    const int y0 = 2 * py, x0 = 2 * px;
    const int tid = threadIdx.x;
    const int b = tid & 31, slot = tid >> 5;

    __shared__ float ws[3584];  // [8co][16ci][28 padded]
    __shared__ float bs[8];
    for (int i = tid; i < 3200; i += 256) {
        const int co_l = i / 400;
        const int rest = i - co_l * 400;
        const int ci = rest / 25;
        const int j = rest - ci * 25;
        ws[(co_l * 16 + ci) * 28 + j] = w2[cob * 400 + i];
    }
    if (tid < 8) bs[tid] = b2[cob + tid];
    __syncthreads();

    const int co = cob + slot;
    const float bias = bs[slot];
    const float* __restrict__ wsl = ws + slot * 448;  // + ci*28
    const float* __restrict__ base = zp1a + ((size_t)(y0 * 30 + x0)) * 32 + b;

    float v[4] = {0.f,0.f,0.f,0.f};
    float cu[4] = {0.f,0.f,0.f,0.f};
    float xrA[36], xrB[36];

    for (int t = 0; t < T_STEPS; ++t) {
        const float* __restrict__ bt = base + (size_t)t * 460800;
        float acc[4] = {0.f, 0.f, 0.f, 0.f};

        LOADWIN(xrA, bt, 960);  // ci = 0
        #pragma unroll 1
        for (int cp = 0; cp < 8; ++cp) {
            const float* __restrict__ bci = bt + 2 * cp * 28800;
            LOADWIN(xrB, bci + 28800, 960);           // ci = 2cp+1 in flight
            FMA25(xrA, wsl + (2 * cp) * 28, acc);     // consume ci = 2cp
            if (cp < 7) LOADWIN(xrA, bci + 2 * 28800, 960);  // ci = 2cp+2 in flight
            FMA25(xrB, wsl + (2 * cp + 1) * 28, acc); // consume ci = 2cp+1
        }

        float zmax = 0.f;
        #pragma unroll
        for (int q = 0; q < 4; ++q) {
            const float inp = 10.f * (acc[q] + bias);
            const float vv = v[q], cur = cu[q];
            const float vd = vv + 0.1f * (cur - vv);
            const float id = 0.8f * cur;
            const float z = (vd - 1.0f > 0.0f) ? 1.0f : 0.0f;
            v[q] = (z > 0.f) ? 0.f : vd;
            cu[q] = id + inp;
            zmax = fmaxf(zmax, z);
        }
        zp2a[(size_t)t * 173056 + (co * 169 + pos) * 32 + b] = zmax;
    }
}

// ---------------- K3: FC as LDS-tiled GEMM ----------------
__global__ __launch_bounds__(256) void k3_gemm(
    const float* __restrict__ zp2a,  // [32t][5408][32b]
    const float* __restrict__ fw,    // [500,5408]
    float* __restrict__ part)        // [8kc][512n][1024col]
{
    const int nt = blockIdx.x, mt = blockIdx.y, kc = blockIdx.z;
    const int tid = threadIdx.x;
    const int cx = tid & 31, ry = tid >> 5;
    const int c0 = nt * 128, m0 = mt * 64, k0 = kc * 676;

    __shared__ float A[26][64];    // [k][n]
    __shared__ float Bs[26][128];  // [k][col]

    float acc[8][4] = {};

    for (int ks = 0; ks < 26; ++ks) {
        const int kb = k0 + ks * 26;
        __syncthreads();
        for (int i = tid; i < 1664; i += 256) {
            const int row = i / 26, kk = i - row * 26;
            int n = m0 + row; if (n > 499) n = 499;
            A[kk][row] = fw[n * 5408 + kb + kk];
        }
        for (int i = tid; i < 3328; i += 256) {
            const int kk = i >> 7, c = i & 127;
            const int col = c0 + c;
            Bs[kk][c] = zp2a[(size_t)(col >> 5) * 173056 + (kb + kk) * 32 + (col & 31)];
        }
        __syncthreads();

        for (int kk = 0; kk < 26; ++kk) {
            const float4 b4 = *(const float4*)&Bs[kk][cx * 4];
            const float4 a0 = *(const float4*)&A[kk][ry * 8];
            const float4 a1 = *(const float4*)&A[kk][ry * 8 + 4];
            const float av[8] = {a0.x, a0.y, a0.z, a0.w, a1.x, a1.y, a1.z, a1.w};
            const float bv[4] = {b4.x, b4.y, b4.z, b4.w};
            #pragma unroll
            for (int i2 = 0; i2 < 8; ++i2)
                #pragma unroll
                for (int j = 0; j < 4; ++j)
                    acc[i2][j] = fmaf(av[i2], bv[j], acc[i2][j]);
        }
    }

    float* pp = part + ((size_t)kc * 512 + m0) * 1024 + c0;
    #pragma unroll
    for (int i2 = 0; i2 < 8; ++i2) {
        const int row = ry * 8 + i2;
        float4 o; o.x = acc[i2][0]; o.y = acc[i2][1]; o.z = acc[i2][2]; o.w = acc[i2][3];
        *(float4*)&pp[row * 1024 + cx * 4] = o;
    }
}

// ---------------- K3b: reduce partials + bias + LIF scan over t ----------------
__global__ __launch_bounds__(256) void k3b_lif(
    const float* __restrict__ part,  // [8kc][512n][1024col], col = t*32+b
    const float* __restrict__ fb,    // [500]
    float* __restrict__ za)          // [32t][500][32]
{
    const int idx = blockIdx.x * 256 + threadIdx.x;
    if (idx >= 16000) return;
    const int n = idx >> 5, b = idx & 31;
    const float bias = fb[n];

    float v = 0.f, cu = 0.f;
    for (int t = 0; t < T_STEPS; ++t) {
        float s = 0.f;
        #pragma unroll
        for (int p = 0; p < 8; ++p)
            s += part[(size_t)p * 524288 + n * 1024 + t * 32 + b];
        s += bias;

        const float vd = v + 0.1f * (cu - v);
        const float id = 0.8f * cu;
        const float z = (vd - 1.0f > 0.0f) ? 1.0f : 0.0f;
        v = (z > 0.f) ? 0.f : vd;
        cu = id + s;
        za[(size_t)t * 16000 + idx] = z;
    }
}

// ---------------- K4: readout dots per (c,t) ----------------
__global__ __launch_bounds__(256) void k4_dot(
    const float* __restrict__ za,   // [32t][500][32]
    const float* __restrict__ ow,   // [10,500]
    float* __restrict__ dota)       // [32t][10][32]
{
    const int c = blockIdx.x, t = blockIdx.y;
    const int tid = threadIdx.x;
    const int b = tid & 31, nc = tid >> 5;
    const float* __restrict__ wr = ow + c * 500;
    const float* __restrict__ zt = za + (size_t)t * 16000;

    float acc = 0.f;
    for (int j = 0; j < 63; ++j) {
        const int n = nc * 63 + j;
        if (n < 500) acc = fmaf(zt[n * 32 + b], wr[n], acc);
    }

    __shared__ float red[256];
    red[tid] = acc;
    __syncthreads();
    if (tid < 32) {
        float dot = 0.f;
        #pragma unroll
        for (int q = 0; q < 8; ++q) dot += red[q * 32 + tid];
        dota[((size_t)t * 10 + c) * 32 + tid] = dot;
    }
}

// ---------------- K5: LI scan + output ----------------
__global__ __launch_bounds__(320) void k5_li(
    const float* __restrict__ dota,  // [32t][10][32]
    float* __restrict__ outp)        // [32t][32b][10c]
{
    const int tid = threadIdx.x;
    if (tid >= 320) return;
    const int c = tid / 32, b = tid & 31;

    float vo = 0.f, io = 0.f;
    for (int t = 0; t < T_STEPS; ++t) {
        const float vout = vo + 0.1f * (io - vo);
        outp[t * 320 + b * 10 + c] = vout;
        vo = vout;
        io = 0.8f * io + dota[(t * 10 + c) * 32 + b];
    }
}

extern "C" void kernel_launch(void* const* d_in, const int* in_sizes, int n_in,
                              void* d_out, int out_size, void* d_ws, size_t ws_size,
                              hipStream_t stream) {
    const float* x  = (const float*)d_in[0];  // [32,32,1,64,64]
    const float* w1 = (const float*)d_in[1];
    const float* b1 = (const float*)d_in[2];
    const float* w2 = (const float*)d_in[3];
    const float* b2 = (const float*)d_in[4];
    const float* fw = (const float*)d_in[5];
    const float* fb = (const float*)d_in[6];
    const float* ow = (const float*)d_in[7];
    float* out = (float*)d_out;
    float* ws = (float*)d_ws;

    size_t off = 0;
    float* xT   = ws + off; off += 4194304;   // [32t][64][64][32b]; dead after k1
    float* zp1a = ws + off; off += 14745600;  // [32t][16*30*30][32b]
    float* zp2a = ws + off; off += 5537792;   // [32t][5408][32b]
    float* za   = ws + off; off += 512000;    // [32t][500][32b]
    float* dota = ws + off; off += 10240;     // [32t][10][32b]
    float* part = xT;                         // alias: [8][512][1024] = 4194304 floats
    // ~100 MB total; every buffer fully written before read (no memset needed).

    k_tr    <<<dim3(64, 32), 256, 0, stream>>>(x, xT);
    k1_conv1<<<900, 256, 0, stream>>>(xT, w1, b1, zp1a);
    k2_conv2<<<676, 256, 0, stream>>>(zp1a, w2, b2, zp2a);
    k3_gemm <<<dim3(8, 8, 8), 256, 0, stream>>>(zp2a, fw, part);
    k3b_lif <<<63, 256, 0, stream>>>(part, fb, za);
    k4_dot  <<<dim3(10, 32), 256, 0, stream>>>(za, ow, dota);
    k5_li   <<<1, 320, 0, stream>>>(dota, out);
}

// Round 9
// 415.357 us; speedup vs baseline: 35.9144x; 2.3547x over previous
//
#include <hip/hip_runtime.h>

// SNN: v_dec = v + 0.1*(i - v); i_dec = 0.8*i; spike if v_dec > 1.0
// v' = spike ? 0 : v_dec; i' = i_dec + input.

#define T_STEPS 32

typedef __bf16 bf16x8 __attribute__((ext_vector_type(8)));
typedef float f32x16 __attribute__((ext_vector_type(16)));
typedef int i32x4 __attribute__((ext_vector_type(4)));

// Bijective XCD-chunked block swizzle (m204).
__device__ __forceinline__ int xcd_swz(int orig, int nwg) {
    const int q = nwg >> 3, r = nwg & 7;
    const int xcd = orig & 7, idx = orig >> 3;
    return (xcd < r ? xcd * (q + 1) : r * (q + 1) + (xcd - r) * q) + idx;
}

// ---------------- K0: transpose x [t][b][64][64] -> xT [t][y][x][b] ----------------
__global__ __launch_bounds__(256) void k_tr(
    const float* __restrict__ x, float* __restrict__ xT)
{
    const int y = blockIdx.x, t = blockIdx.y;
    const int tid = threadIdx.x;
    __shared__ float tile[32][65];

    const int lx = tid & 63, bg = tid >> 6;
    #pragma unroll
    for (int p = 0; p < 8; ++p) {
        const int b = bg + p * 4;
        tile[b][lx] = x[((size_t)(t * 32 + b) * 64 + y) * 64 + lx];
    }
    __syncthreads();
    const int wb = tid & 31, xg = tid >> 5;
    #pragma unroll
    for (int p = 0; p < 8; ++p) {
        const int xx = xg + p * 8;
        xT[((size_t)(t * 64 + y) * 64 + xx) * 32 + wb] = tile[wb][xx];
    }
}

// ---------------- K1: conv1 (1->16) + LIF + pool, ALL timesteps (round-6 form) --------
__global__ __launch_bounds__(256) void k1_conv1(
    const float* __restrict__ xT,    // [32t,64,64,32b]
    const float* __restrict__ w1,    // [16,1,5,5]
    const float* __restrict__ b1,    // [16]
    float* __restrict__ zp1a)        // [32t][16,30,30,32b]
{
    const int pos = xcd_swz(blockIdx.x, 900);
    const int py = pos / 30, px = pos % 30;
    const int y0 = 2 * py, x0 = 2 * px;
    const int tid = threadIdx.x;
    const int b = tid & 31, slot = tid >> 5;

    __shared__ float ws[400];
    for (int i = tid; i < 400; i += 256) ws[i] = w1[i];
    __syncthreads();
    const float bias0 = b1[slot], bias1 = b1[slot + 8];

    float v[2][4] = {{0.f,0.f,0.f,0.f},{0.f,0.f,0.f,0.f}};
    float cu[2][4] = {{0.f,0.f,0.f,0.f},{0.f,0.f,0.f,0.f}};

    for (int t = 0; t < T_STEPS; ++t) {
        float xr[36];
        const float* __restrict__ bt =
            xT + ((size_t)(t * 64 + y0) * 64 + x0) * 32 + b;
        #pragma unroll
        for (int r = 0; r < 6; ++r) {
            const float* __restrict__ pr = bt + r * 2048;
            #pragma unroll
            for (int c = 0; c < 6; ++c) xr[r * 6 + c] = pr[c * 32];
        }

        #pragma unroll
        for (int half = 0; half < 2; ++half) {
            const int co = slot + 8 * half;
            const float* wc = ws + co * 25;
            float acc[4] = {0.f, 0.f, 0.f, 0.f};
            #pragma unroll
            for (int ky = 0; ky < 5; ++ky) {
                #pragma unroll
                for (int kx = 0; kx < 5; ++kx) {
                    const float w = wc[ky * 5 + kx];
                    acc[0] = fmaf(w, xr[ky * 6 + kx],           acc[0]);
                    acc[1] = fmaf(w, xr[ky * 6 + kx + 1],       acc[1]);
                    acc[2] = fmaf(w, xr[(ky + 1) * 6 + kx],     acc[2]);
                    acc[3] = fmaf(w, xr[(ky + 1) * 6 + kx + 1], acc[3]);
                }
            }
            const float bias = half ? bias1 : bias0;
            float zmax = 0.f;
            #pragma unroll
            for (int q = 0; q < 4; ++q) {
                const float inp = acc[q] + bias;
                const float vv = v[half][q], cur = cu[half][q];
                const float vd = vv + 0.1f * (cur - vv);
                const float id = 0.8f * cur;
                const float z = (vd - 1.0f > 0.0f) ? 1.0f : 0.0f;
                v[half][q] = (z > 0.f) ? 0.f : vd;
                cu[half][q] = id + inp;
                zmax = fmaxf(zmax, z);
            }
            zp1a[(size_t)t * 460800 + ((co * 30 + py) * 30 + px) * 32 + b] = zmax;
        }
    }
}

// ---------------- K2w: 3-way bf16 split of conv2 weights ----------------
// wsplit[3][25tap][32co][16ci] as u16 bf16 bits. hi+mid+lo == fp32 w (<=1 ulp).
__global__ __launch_bounds__(256) void k2w_split(
    const float* __restrict__ w2, unsigned short* __restrict__ wsplit)
{
    const int i = blockIdx.x * 256 + threadIdx.x;
    if (i >= 12800) return;
    const int co = i / 400, rest = i % 400;
    const int ci = rest / 25, tap = rest % 25;
    const float w = w2[i];
    const unsigned wb = __float_as_uint(w);
    const unsigned hi = wb & 0xFFFF0000u;
    const float r1 = w - __uint_as_float(hi);
    const unsigned mid = __float_as_uint(r1) & 0xFFFF0000u;
    const float r2 = r1 - __uint_as_float(mid);
    const unsigned lo = __float_as_uint(r2) & 0xFFFF0000u;
    const int base = (tap * 32 + co) * 16 + ci;
    wsplit[base]         = (unsigned short)(hi >> 16);
    wsplit[12800 + base] = (unsigned short)(mid >> 16);
    wsplit[25600 + base] = (unsigned short)(lo >> 16);
}

// ---------------- K2a: conv2 as MFMA GEMM (unfused), ALL (pool-group, t) tasks --------
// wave-task = one 2x2 pool group at one t: C[32co x 32b] per quadrant.
// Tap decomposition: per window cell, ONE B-frag (16ci x 32b spikes, exact bf16)
// reused by every tap that touches the cell. Weights: 3-way bf16 split in LDS.
__global__ __launch_bounds__(256, 2) void k2a_mfma(
    const float* __restrict__ zp1a,          // [32t][16ci][30][30][32b]
    const unsigned short* __restrict__ wsplit,
    float* __restrict__ raw)                 // [32t][169pg][4q][32co][32b]
{
    __shared__ i32x4 wlds[4800];  // [3sp][25tap][32co][2cig] 16B chunks
    const int tid = threadIdx.x;
    for (int i = tid; i < 4800; i += 256)
        wlds[i] = ((const i32x4*)wsplit)[i];
    __syncthreads();

    const int w = tid >> 6, l = tid & 63;
    const int task = xcd_swz(blockIdx.x, 1352) * 4 + w;
    const int t = task / 169, pg = task % 169;
    const int py = pg / 13, px = pg % 13;
    const int b = l & 31, cig = l >> 5;
    const int abase = (l & 31) * 2 + cig;

    const float* __restrict__ zt =
        zp1a + (size_t)t * 460800 + cig * 230400 + ((2 * py) * 30 + 2 * px) * 32 + b;

    f32x16 accA, accB, accC, accD;
    #pragma unroll
    for (int r = 0; r < 16; ++r) { accA[r] = 0.f; accB[r] = 0.f; accC[r] = 0.f; accD[r] = 0.f; }

    #pragma unroll
    for (int wy = 0; wy < 6; ++wy) {
        // ---- load + pack 6 cell fragments of window row wy (spikes exact: >>16) ----
        i32x4 bw[6];
        #pragma unroll
        for (int wx = 0; wx < 6; ++wx) {
            const float* __restrict__ c = zt + (wy * 30 + wx) * 32;
            unsigned x0 = __float_as_uint(c[0]);
            unsigned x1 = __float_as_uint(c[28800]);
            unsigned x2 = __float_as_uint(c[57600]);
            unsigned x3 = __float_as_uint(c[86400]);
            unsigned x4 = __float_as_uint(c[115200]);
            unsigned x5 = __float_as_uint(c[144000]);
            unsigned x6 = __float_as_uint(c[172800]);
            unsigned x7 = __float_as_uint(c[201600]);
            bw[wx][0] = (int)((x0 >> 16) | (x1 & 0xFFFF0000u));
            bw[wx][1] = (int)((x2 >> 16) | (x3 & 0xFFFF0000u));
            bw[wx][2] = (int)((x4 >> 16) | (x5 & 0xFFFF0000u));
            bw[wx][3] = (int)((x6 >> 16) | (x7 & 0xFFFF0000u));
        }
        // ---- quadrant row qy=0 uses tap row ky=wy ----
        if (wy <= 4) {
            #pragma unroll
            for (int sp = 0; sp < 3; ++sp) {
                #pragma unroll
                for (int kx = 0; kx < 5; ++kx) {
                    const int tap = wy * 5 + kx;
                    const bf16x8 A = __builtin_bit_cast(bf16x8, wlds[(sp * 25 + tap) * 64 + abase]);
                    accA = __builtin_amdgcn_mfma_f32_32x32x16_bf16(
                        A, __builtin_bit_cast(bf16x8, bw[kx]),     accA, 0, 0, 0);
                    accB = __builtin_amdgcn_mfma_f32_32x32x16_bf16(
                        A, __builtin_bit_cast(bf16x8, bw[kx + 1]), accB, 0, 0, 0);
                }
            }
        }
        // ---- quadrant row qy=1 uses tap row ky=wy-1 ----
        if (wy >= 1) {
            #pragma unroll
            for (int sp = 0; sp < 3; ++sp) {
                #pragma unroll
                for (int kx = 0; kx < 5; ++kx) {
                    const int tap = (wy - 1) * 5 + kx;
                    const bf16x8 A = __builtin_bit_cast(bf16x8, wlds[(sp * 25 + tap) * 64 + abase]);
                    accC = __builtin_amdgcn_mfma_f32_32x32x16_bf16(
                        A, __builtin_bit_cast(bf16x8, bw[kx]),     accC, 0, 0, 0);
                    accD = __builtin_amdgcn_mfma_f32_32x32x16_bf16(
                        A, __builtin_bit_cast(bf16x8, bw[kx + 1]), accD, 0, 0, 0);
                }
            }
        }
    }

    // ---- store raw conv outputs: C row = co = (r&3)+8*(r>>2)+4*hi, col = b ----
    float* __restrict__ rp = raw + (size_t)(t * 169 + pg) * 4096 + b;
    const int hi = l >> 5;
    #pragma unroll
    for (int r = 0; r < 16; ++r) {
        const int row = (r & 3) + 8 * (r >> 2) + 4 * hi;
        rp[row * 32]        = accA[r];
        rp[1024 + row * 32] = accB[r];
        rp[2048 + row * 32] = accC[r];
        rp[3072 + row * 32] = accD[r];
    }
}

// ---------------- K2b: LIF + pool scan over t (state in regs) ----------------
// grid 676 = 169pg x 4 co-groups; thread owns (pg, co, b) with 4 quadrant states.
__global__ __launch_bounds__(256) void k2b_lifpool(
    const float* __restrict__ raw,   // [32t][169pg][4q][32co][32b]
    const float* __restrict__ b2,
    float* __restrict__ zp2a)        // [32t][5408][32b]
{
    const int bid = blockIdx.x;
    const int pg = bid >> 2, cog = bid & 3;
    const int tid = threadIdx.x;
    const int co = cog * 8 + (tid >> 5), b = tid & 31;
    const float bias = b2[co];
    const float* __restrict__ rp = raw + (size_t)pg * 4096 + co * 32 + b;

    float v0=0.f,v1=0.f,v2=0.f,v3=0.f, c0=0.f,c1=0.f,c2=0.f,c3=0.f;
    for (int t = 0; t < T_STEPS; ++t) {
        const float* __restrict__ r = rp + (size_t)t * 692224;  // 169*4096
        float zm = 0.f;
        { const float inp = 10.f*(r[0]    + bias); const float vd = v0 + 0.1f*(c0-v0);
          const float z = (vd-1.f>0.f)?1.f:0.f; v0 = (z>0.f)?0.f:vd; c0 = 0.8f*c0 + inp;
          zm = fmaxf(zm, z); }
        { const float inp = 10.f*(r[1024] + bias); const float vd = v1 + 0.1f*(c1-v1);
          const float z = (vd-1.f>0.f)?1.f:0.f; v1 = (z>0.f)?0.f:vd; c1 = 0.8f*c1 + inp;
          zm = fmaxf(zm, z); }
        { const float inp = 10.f*(r[2048] + bias); const float vd = v2 + 0.1f*(c2-v2);
          const float z = (vd-1.f>0.f)?1.f:0.f; v2 = (z>0.f)?0.f:vd; c2 = 0.8f*c2 + inp;
          zm = fmaxf(zm, z); }
        { const float inp = 10.f*(r[3072] + bias); const float vd = v3 + 0.1f*(c3-v3);
          const float z = (vd-1.f>0.f)?1.f:0.f; v3 = (z>0.f)?0.f:vd; c3 = 0.8f*c3 + inp;
          zm = fmaxf(zm, z); }
        zp2a[(size_t)t * 173056 + (co * 169 + pg) * 32 + b] = zm;
    }
}

// ---------------- K3: FC as LDS-tiled GEMM ----------------
__global__ __launch_bounds__(256) void k3_gemm(
    const float* __restrict__ zp2a,  // [32t][5408][32b]
    const float* __restrict__ fw,    // [500,5408]
    float* __restrict__ part)        // [8kc][512n][1024col]
{
    const int nt = blockIdx.x, mt = blockIdx.y, kc = blockIdx.z;
    const int tid = threadIdx.x;
    const int cx = tid & 31, ry = tid >> 5;
    const int c0 = nt * 128, m0 = mt * 64, k0 = kc * 676;

    __shared__ float A[26][64];
    __shared__ float Bs[26][128];

    float acc[8][4] = {};

    for (int ks = 0; ks < 26; ++ks) {
        const int kb = k0 + ks * 26;
        __syncthreads();
        for (int i = tid; i < 1664; i += 256) {
            const int row = i / 26, kk = i - row * 26;
            int n = m0 + row; if (n > 499) n = 499;
            A[kk][row] = fw[n * 5408 + kb + kk];
        }
        for (int i = tid; i < 3328; i += 256) {
            const int kk = i >> 7, c = i & 127;
            const int col = c0 + c;
            Bs[kk][c] = zp2a[(size_t)(col >> 5) * 173056 + (kb + kk) * 32 + (col & 31)];
        }
        __syncthreads();

        for (int kk = 0; kk < 26; ++kk) {
            const float4 b4 = *(const float4*)&Bs[kk][cx * 4];
            const float4 a0 = *(const float4*)&A[kk][ry * 8];
            const float4 a1 = *(const float4*)&A[kk][ry * 8 + 4];
            const float av[8] = {a0.x, a0.y, a0.z, a0.w, a1.x, a1.y, a1.z, a1.w};
            const float bv[4] = {b4.x, b4.y, b4.z, b4.w};
            #pragma unroll
            for (int i2 = 0; i2 < 8; ++i2)
                #pragma unroll
                for (int j = 0; j < 4; ++j)
                    acc[i2][j] = fmaf(av[i2], bv[j], acc[i2][j]);
        }
    }

    float* pp = part + ((size_t)kc * 512 + m0) * 1024 + c0;
    #pragma unroll
    for (int i2 = 0; i2 < 8; ++i2) {
        const int row = ry * 8 + i2;
        float4 o; o.x = acc[i2][0]; o.y = acc[i2][1]; o.z = acc[i2][2]; o.w = acc[i2][3];
        *(float4*)&pp[row * 1024 + cx * 4] = o;
    }
}

// ---------------- K3b: reduce partials + bias + LIF scan over t ----------------
__global__ __launch_bounds__(256) void k3b_lif(
    const float* __restrict__ part,
    const float* __restrict__ fb,
    float* __restrict__ za)          // [32t][500][32]
{
    const int idx = blockIdx.x * 256 + threadIdx.x;
    if (idx >= 16000) return;
    const int n = idx >> 5, b = idx & 31;
    const float bias = fb[n];

    float v = 0.f, cu = 0.f;
    for (int t = 0; t < T_STEPS; ++t) {
        float s = 0.f;
        #pragma unroll
        for (int p = 0; p < 8; ++p)
            s += part[(size_t)p * 524288 + n * 1024 + t * 32 + b];
        s += bias;

        const float vd = v + 0.1f * (cu - v);
        const float id = 0.8f * cu;
        const float z = (vd - 1.0f > 0.0f) ? 1.0f : 0.0f;
        v = (z > 0.f) ? 0.f : vd;
        cu = id + s;
        za[(size_t)t * 16000 + idx] = z;
    }
}

// ---------------- K4: readout dots per (c,t) ----------------
__global__ __launch_bounds__(256) void k4_dot(
    const float* __restrict__ za,
    const float* __restrict__ ow,
    float* __restrict__ dota)
{
    const int c = blockIdx.x, t = blockIdx.y;
    const int tid = threadIdx.x;
    const int b = tid & 31, nc = tid >> 5;
    const float* __restrict__ wr = ow + c * 500;
    const float* __restrict__ zt = za + (size_t)t * 16000;

    float acc = 0.f;
    for (int j = 0; j < 63; ++j) {
        const int n = nc * 63 + j;
        if (n < 500) acc = fmaf(zt[n * 32 + b], wr[n], acc);
    }

    __shared__ float red[256];
    red[tid] = acc;
    __syncthreads();
    if (tid < 32) {
        float dot = 0.f;
        #pragma unroll
        for (int q = 0; q < 8; ++q) dot += red[q * 32 + tid];
        dota[((size_t)t * 10 + c) * 32 + tid] = dot;
    }
}

// ---------------- K5: LI scan + output ----------------
__global__ __launch_bounds__(320) void k5_li(
    const float* __restrict__ dota,
    float* __restrict__ outp)
{
    const int tid = threadIdx.x;
    if (tid >= 320) return;
    const int c = tid / 32, b = tid & 31;

    float vo = 0.f, io = 0.f;
    for (int t = 0; t < T_STEPS; ++t) {
        const float vout = vo + 0.1f * (io - vo);
        outp[t * 320 + b * 10 + c] = vout;
        vo = vout;
        io = 0.8f * io + dota[(t * 10 + c) * 32 + b];
    }
}

extern "C" void kernel_launch(void* const* d_in, const int* in_sizes, int n_in,
                              void* d_out, int out_size, void* d_ws, size_t ws_size,
                              hipStream_t stream) {
    const float* x  = (const float*)d_in[0];
    const float* w1 = (const float*)d_in[1];
    const float* b1 = (const float*)d_in[2];
    const float* w2 = (const float*)d_in[3];
    const float* b2 = (const float*)d_in[4];
    const float* fw = (const float*)d_in[5];
    const float* fb = (const float*)d_in[6];
    const float* ow = (const float*)d_in[7];
    float* out = (float*)d_out;
    float* ws = (float*)d_ws;

    size_t off = 0;
    float* zp1a = ws + off; off += 14745600;  // [32t][16*30*30][32b]
    float* zp2a = ws + off; off += 5537792;   // [32t][5408][32b]
    float* za   = ws + off; off += 512000;    // [32t][500][32b]
    float* dota = ws + off; off += 10240;     // [32t][10][32b]
    unsigned short* wsplit = (unsigned short*)(ws + off); off += 19200; // 3x25x32x16 u16
    float* big  = ws + off; off += 22151168;  // union: xT(4.2M) / conv2raw(22.2M) / part(4.2M)
    // total ~43.0M floats = 172 MB; every region fully written before read.

    float* xT       = big;
    float* conv2raw = big;
    float* part     = big;

    k2w_split<<<50, 256, 0, stream>>>(w2, wsplit);
    k_tr     <<<dim3(64, 32), 256, 0, stream>>>(x, xT);
    k1_conv1 <<<900, 256, 0, stream>>>(xT, w1, b1, zp1a);
    k2a_mfma <<<1352, 256, 0, stream>>>(zp1a, wsplit, conv2raw);
    k2b_lifpool<<<676, 256, 0, stream>>>(conv2raw, b2, zp2a);
    k3_gemm  <<<dim3(8, 8, 8), 256, 0, stream>>>(zp2a, fw, part);
    k3b_lif  <<<63, 256, 0, stream>>>(part, fb, za);
    k4_dot   <<<dim3(10, 32), 256, 0, stream>>>(za, ow, dota);
    k5_li    <<<1, 320, 0, stream>>>(dota, out);
}

// Round 10
// 262.517 us; speedup vs baseline: 56.8242x; 1.5822x over previous
//
#include <hip/hip_runtime.h>

// SNN: v_dec = v + 0.1*(i - v); i_dec = 0.8*i; spike if v_dec > 1.0
// v' = spike ? 0 : v_dec; i' = i_dec + input.

#define T_STEPS 32

typedef __bf16 bf16x8 __attribute__((ext_vector_type(8)));
typedef float f32x16 __attribute__((ext_vector_type(16)));
typedef int i32x4 __attribute__((ext_vector_type(4)));

// Bijective XCD-chunked block swizzle (m204).
__device__ __forceinline__ int xcd_swz(int orig, int nwg) {
    const int q = nwg >> 3, r = nwg & 7;
    const int xcd = orig & 7, idx = orig >> 3;
    return (xcd < r ? xcd * (q + 1) : r * (q + 1) + (xcd - r) * q) + idx;
}

// ---------------- K0: transpose x [t][b][64][64] -> xT [t][y][x][b] ----------------
__global__ __launch_bounds__(256) void k_tr(
    const float* __restrict__ x, float* __restrict__ xT)
{
    const int y = blockIdx.x, t = blockIdx.y;
    const int tid = threadIdx.x;
    __shared__ float tile[32][65];

    const int lx = tid & 63, bg = tid >> 6;
    #pragma unroll
    for (int p = 0; p < 8; ++p) {
        const int b = bg + p * 4;
        tile[b][lx] = x[((size_t)(t * 32 + b) * 64 + y) * 64 + lx];
    }
    __syncthreads();
    const int wb = tid & 31, xg = tid >> 5;
    #pragma unroll
    for (int p = 0; p < 8; ++p) {
        const int xx = xg + p * 8;
        xT[((size_t)(t * 64 + y) * 64 + xx) * 32 + wb] = tile[wb][xx];
    }
}

// ---------------- K1: conv1 (1->16) + LIF + pool, ALL timesteps ----------------
__global__ __launch_bounds__(256) void k1_conv1(
    const float* __restrict__ xT,    // [32t,64,64,32b]
    const float* __restrict__ w1,    // [16,1,5,5]
    const float* __restrict__ b1,    // [16]
    float* __restrict__ zp1a)        // [32t][16,30,30,32b]
{
    const int pos = xcd_swz(blockIdx.x, 900);
    const int py = pos / 30, px = pos % 30;
    const int y0 = 2 * py, x0 = 2 * px;
    const int tid = threadIdx.x;
    const int b = tid & 31, slot = tid >> 5;

    __shared__ float ws[400];
    for (int i = tid; i < 400; i += 256) ws[i] = w1[i];
    __syncthreads();
    const float bias0 = b1[slot], bias1 = b1[slot + 8];

    float v[2][4] = {{0.f,0.f,0.f,0.f},{0.f,0.f,0.f,0.f}};
    float cu[2][4] = {{0.f,0.f,0.f,0.f},{0.f,0.f,0.f,0.f}};

    for (int t = 0; t < T_STEPS; ++t) {
        float xr[36];
        const float* __restrict__ bt =
            xT + ((size_t)(t * 64 + y0) * 64 + x0) * 32 + b;
        #pragma unroll
        for (int r = 0; r < 6; ++r) {
            const float* __restrict__ pr = bt + r * 2048;
            #pragma unroll
            for (int c = 0; c < 6; ++c) xr[r * 6 + c] = pr[c * 32];
        }

        #pragma unroll
        for (int half = 0; half < 2; ++half) {
            const int co = slot + 8 * half;
            const float* wc = ws + co * 25;
            float acc[4] = {0.f, 0.f, 0.f, 0.f};
            #pragma unroll
            for (int ky = 0; ky < 5; ++ky) {
                #pragma unroll
                for (int kx = 0; kx < 5; ++kx) {
                    const float w = wc[ky * 5 + kx];
                    acc[0] = fmaf(w, xr[ky * 6 + kx],           acc[0]);
                    acc[1] = fmaf(w, xr[ky * 6 + kx + 1],       acc[1]);
                    acc[2] = fmaf(w, xr[(ky + 1) * 6 + kx],     acc[2]);
                    acc[3] = fmaf(w, xr[(ky + 1) * 6 + kx + 1], acc[3]);
                }
            }
            const float bias = half ? bias1 : bias0;
            float zmax = 0.f;
            #pragma unroll
            for (int q = 0; q < 4; ++q) {
                const float inp = acc[q] + bias;
                const float vv = v[half][q], cur = cu[half][q];
                const float vd = vv + 0.1f * (cur - vv);
                const float id = 0.8f * cur;
                const float z = (vd - 1.0f > 0.0f) ? 1.0f : 0.0f;
                v[half][q] = (z > 0.f) ? 0.f : vd;
                cu[half][q] = id + inp;
                zmax = fmaxf(zmax, z);
            }
            zp1a[(size_t)t * 460800 + ((co * 30 + py) * 30 + px) * 32 + b] = zmax;
        }
    }
}

// ---------------- K2w: 3-way bf16 split of conv2 weights ----------------
__global__ __launch_bounds__(256) void k2w_split(
    const float* __restrict__ w2, unsigned short* __restrict__ wsplit)
{
    const int i = blockIdx.x * 256 + threadIdx.x;
    if (i >= 12800) return;
    const int co = i / 400, rest = i % 400;
    const int ci = rest / 25, tap = rest % 25;
    const float w = w2[i];
    const unsigned wb = __float_as_uint(w);
    const unsigned hi = wb & 0xFFFF0000u;
    const float r1 = w - __uint_as_float(hi);
    const unsigned mid = __float_as_uint(r1) & 0xFFFF0000u;
    const float r2 = r1 - __uint_as_float(mid);
    const unsigned lo = __float_as_uint(r2) & 0xFFFF0000u;
    const int base = (tap * 32 + co) * 16 + ci;
    wsplit[base]         = (unsigned short)(hi >> 16);
    wsplit[12800 + base] = (unsigned short)(mid >> 16);
    wsplit[25600 + base] = (unsigned short)(lo >> 16);
}

// ---------------- K2a: conv2 as MFMA GEMM (unfused) ----------------
__global__ __launch_bounds__(256, 2) void k2a_mfma(
    const float* __restrict__ zp1a,          // [32t][16ci][30][30][32b]
    const unsigned short* __restrict__ wsplit,
    float* __restrict__ raw)                 // [32t][169pg][4q][32co][32b]
{
    __shared__ i32x4 wlds[4800];  // [3sp][25tap][32co][2cig]
    const int tid = threadIdx.x;
    for (int i = tid; i < 4800; i += 256)
        wlds[i] = ((const i32x4*)wsplit)[i];
    __syncthreads();

    const int w = tid >> 6, l = tid & 63;
    const int task = xcd_swz(blockIdx.x, 1352) * 4 + w;
    const int t = task / 169, pg = task % 169;
    const int py = pg / 13, px = pg % 13;
    const int b = l & 31, cig = l >> 5;
    const int abase = (l & 31) * 2 + cig;

    const float* __restrict__ zt =
        zp1a + (size_t)t * 460800 + cig * 230400 + ((2 * py) * 30 + 2 * px) * 32 + b;

    f32x16 accA, accB, accC, accD;
    #pragma unroll
    for (int r = 0; r < 16; ++r) { accA[r] = 0.f; accB[r] = 0.f; accC[r] = 0.f; accD[r] = 0.f; }

    #pragma unroll
    for (int wy = 0; wy < 6; ++wy) {
        i32x4 bw[6];
        #pragma unroll
        for (int wx = 0; wx < 6; ++wx) {
            const float* __restrict__ c = zt + (wy * 30 + wx) * 32;
            unsigned x0 = __float_as_uint(c[0]);
            unsigned x1 = __float_as_uint(c[28800]);
            unsigned x2 = __float_as_uint(c[57600]);
            unsigned x3 = __float_as_uint(c[86400]);
            unsigned x4 = __float_as_uint(c[115200]);
            unsigned x5 = __float_as_uint(c[144000]);
            unsigned x6 = __float_as_uint(c[172800]);
            unsigned x7 = __float_as_uint(c[201600]);
            bw[wx][0] = (int)((x0 >> 16) | (x1 & 0xFFFF0000u));
            bw[wx][1] = (int)((x2 >> 16) | (x3 & 0xFFFF0000u));
            bw[wx][2] = (int)((x4 >> 16) | (x5 & 0xFFFF0000u));
            bw[wx][3] = (int)((x6 >> 16) | (x7 & 0xFFFF0000u));
        }
        if (wy <= 4) {
            #pragma unroll
            for (int sp = 0; sp < 3; ++sp) {
                #pragma unroll
                for (int kx = 0; kx < 5; ++kx) {
                    const int tap = wy * 5 + kx;
                    const bf16x8 A = __builtin_bit_cast(bf16x8, wlds[(sp * 25 + tap) * 64 + abase]);
                    accA = __builtin_amdgcn_mfma_f32_32x32x16_bf16(
                        A, __builtin_bit_cast(bf16x8, bw[kx]),     accA, 0, 0, 0);
                    accB = __builtin_amdgcn_mfma_f32_32x32x16_bf16(
                        A, __builtin_bit_cast(bf16x8, bw[kx + 1]), accB, 0, 0, 0);
                }
            }
        }
        if (wy >= 1) {
            #pragma unroll
            for (int sp = 0; sp < 3; ++sp) {
                #pragma unroll
                for (int kx = 0; kx < 5; ++kx) {
                    const int tap = (wy - 1) * 5 + kx;
                    const bf16x8 A = __builtin_bit_cast(bf16x8, wlds[(sp * 25 + tap) * 64 + abase]);
                    accC = __builtin_amdgcn_mfma_f32_32x32x16_bf16(
                        A, __builtin_bit_cast(bf16x8, bw[kx]),     accC, 0, 0, 0);
                    accD = __builtin_amdgcn_mfma_f32_32x32x16_bf16(
                        A, __builtin_bit_cast(bf16x8, bw[kx + 1]), accD, 0, 0, 0);
                }
            }
        }
    }

    float* __restrict__ rp = raw + (size_t)(t * 169 + pg) * 4096 + b;
    const int hi = l >> 5;
    #pragma unroll
    for (int r = 0; r < 16; ++r) {
        const int row = (r & 3) + 8 * (r >> 2) + 4 * hi;
        rp[row * 32]        = accA[r];
        rp[1024 + row * 32] = accB[r];
        rp[2048 + row * 32] = accC[r];
        rp[3072 + row * 32] = accD[r];
    }
}

// ---------------- K2b: LIF + pool scan over t ----------------
__global__ __launch_bounds__(256) void k2b_lifpool(
    const float* __restrict__ raw,   // [32t][169pg][4q][32co][32b]
    const float* __restrict__ b2,
    float* __restrict__ zp2a)        // [32t][5408][32b]
{
    const int bid = blockIdx.x;
    const int pg = bid >> 2, cog = bid & 3;
    const int tid = threadIdx.x;
    const int co = cog * 8 + (tid >> 5), b = tid & 31;
    const float bias = b2[co];
    const float* __restrict__ rp = raw + (size_t)pg * 4096 + co * 32 + b;

    float v0=0.f,v1=0.f,v2=0.f,v3=0.f, c0=0.f,c1=0.f,c2=0.f,c3=0.f;
    for (int t = 0; t < T_STEPS; ++t) {
        const float* __restrict__ r = rp + (size_t)t * 692224;
        float zm = 0.f;
        { const float inp = 10.f*(r[0]    + bias); const float vd = v0 + 0.1f*(c0-v0);
          const float z = (vd-1.f>0.f)?1.f:0.f; v0 = (z>0.f)?0.f:vd; c0 = 0.8f*c0 + inp;
          zm = fmaxf(zm, z); }
        { const float inp = 10.f*(r[1024] + bias); const float vd = v1 + 0.1f*(c1-v1);
          const float z = (vd-1.f>0.f)?1.f:0.f; v1 = (z>0.f)?0.f:vd; c1 = 0.8f*c1 + inp;
          zm = fmaxf(zm, z); }
        { const float inp = 10.f*(r[2048] + bias); const float vd = v2 + 0.1f*(c2-v2);
          const float z = (vd-1.f>0.f)?1.f:0.f; v2 = (z>0.f)?0.f:vd; c2 = 0.8f*c2 + inp;
          zm = fmaxf(zm, z); }
        { const float inp = 10.f*(r[3072] + bias); const float vd = v3 + 0.1f*(c3-v3);
          const float z = (vd-1.f>0.f)?1.f:0.f; v3 = (z>0.f)?0.f:vd; c3 = 0.8f*c3 + inp;
          zm = fmaxf(zm, z); }
        zp2a[(size_t)t * 173056 + (co * 169 + pg) * 32 + b] = zm;
    }
}

// ---------------- K3w: 3-way bf16 split of FC weights ----------------
// wf[3sp][16nt][338ks][32n][16k] bf16; rows n>=500 zero-padded.
__global__ __launch_bounds__(256) void k3w_split(
    const float* __restrict__ fw, unsigned short* __restrict__ wf)
{
    const int gid = blockIdx.x * 256 + threadIdx.x;  // 173056 total
    const int l = gid & 31;
    const int ks = (gid >> 5) % 338;
    const int nt = gid / 10816;
    const int n = nt * 32 + l;

    unsigned hipk[8], midpk[8], lopk[8];
    #pragma unroll
    for (int p = 0; p < 8; ++p) {
        unsigned h[2], m[2], o[2];
        #pragma unroll
        for (int e = 0; e < 2; ++e) {
            const float w = (n < 500) ? fw[(size_t)n * 5408 + ks * 16 + 2 * p + e] : 0.f;
            const unsigned wb = __float_as_uint(w);
            const unsigned hi = wb & 0xFFFF0000u;
            const float r1 = w - __uint_as_float(hi);
            const unsigned mid = __float_as_uint(r1) & 0xFFFF0000u;
            const float r2 = r1 - __uint_as_float(mid);
            h[e] = hi >> 16; m[e] = mid >> 16; o[e] = __float_as_uint(r2) >> 16;
        }
        hipk[p]  = h[0] | (h[1] << 16);
        midpk[p] = m[0] | (m[1] << 16);
        lopk[p]  = o[0] | (o[1] << 16);
    }

    i32x4* __restrict__ wv = (i32x4*)wf;
    const int base = (nt * 338 + ks) * 64 + l * 2;  // i32x4 units; sp stride 346112
    i32x4 a, bq;
    a[0]=(int)hipk[0];a[1]=(int)hipk[1];a[2]=(int)hipk[2];a[3]=(int)hipk[3];
    bq[0]=(int)hipk[4];bq[1]=(int)hipk[5];bq[2]=(int)hipk[6];bq[3]=(int)hipk[7];
    wv[base] = a; wv[base + 1] = bq;
    a[0]=(int)midpk[0];a[1]=(int)midpk[1];a[2]=(int)midpk[2];a[3]=(int)midpk[3];
    bq[0]=(int)midpk[4];bq[1]=(int)midpk[5];bq[2]=(int)midpk[6];bq[3]=(int)midpk[7];
    wv[base + 346112] = a; wv[base + 346113] = bq;
    a[0]=(int)lopk[0];a[1]=(int)lopk[1];a[2]=(int)lopk[2];a[3]=(int)lopk[3];
    bq[0]=(int)lopk[4];bq[1]=(int)lopk[5];bq[2]=(int)lopk[6];bq[3]=(int)lopk[7];
    wv[base + 692224] = a; wv[base + 692225] = bq;
}

// ---------------- Zpack: zp2a fp32 -> zb bf16 [32t][338ks][2kh][32b][8k] ----------------
__global__ __launch_bounds__(256) void zpack(
    const float* __restrict__ zp2a, unsigned short* __restrict__ zb)
{
    const int gid = blockIdx.x * 256 + threadIdx.x;  // 692224 total
    const int b = gid & 31;
    const int kh = (gid >> 5) & 1;
    const int rest = gid >> 6;
    const int ks = rest % 338;
    const int t = rest / 338;

    const float* __restrict__ zp = zp2a + (size_t)t * 173056 + (ks * 16 + kh * 8) * 32 + b;
    i32x4 pk;
    #pragma unroll
    for (int p = 0; p < 4; ++p) {
        const unsigned v0 = __float_as_uint(zp[(2 * p) * 32]) >> 16;
        const unsigned v1 = __float_as_uint(zp[(2 * p + 1) * 32]) & 0xFFFF0000u;
        pk[p] = (int)(v0 | v1);
    }
    ((i32x4*)zb)[gid] = pk;
}

// ---------------- K3: FC as MFMA GEMM, no LDS ----------------
// Wave = (nt, 128 cols = 4 coltiles), K-chunk of 26 ksteps. A reused over 4 cols.
// Grid 416 = 8 ntg x (13 kc x 4 cgg), nt-major XCD swizzle (2MB A slice L2-resident).
__global__ __launch_bounds__(256) void k3_mfma(
    const unsigned short* __restrict__ wf,   // [3][16nt][338ks][32n][16k]
    const unsigned short* __restrict__ zb,   // [32t][338ks][2kh][32b][8k]
    float* __restrict__ part)                // [13][512][1024]
{
    const int wgid = xcd_swz(blockIdx.x, 416);
    const int ntg = wgid / 52, rest = wgid % 52;
    const int kc = rest >> 2, cgg = rest & 3;
    const int tid = threadIdx.x;
    const int w = tid >> 6, l = tid & 63;
    const int nt = ntg * 2 + (w >> 1);
    const int cg = cgg * 2 + (w & 1);
    const int lo5 = l & 31, hi1 = l >> 5;

    const i32x4* __restrict__ wv = (const i32x4*)wf;
    const i32x4* __restrict__ zv = (const i32x4*)zb;

    f32x16 acc0, acc1, acc2, acc3;
    #pragma unroll
    for (int r = 0; r < 16; ++r) { acc0[r]=0.f; acc1[r]=0.f; acc2[r]=0.f; acc3[r]=0.f; }

    const int ks0 = kc * 26;
    #pragma unroll 2
    for (int kk = 0; kk < 26; ++kk) {
        const int ks = ks0 + kk;
        const int ab = (nt * 338 + ks) * 64 + lo5 * 2 + hi1;
        const bf16x8 A0 = __builtin_bit_cast(bf16x8, wv[ab]);
        const bf16x8 A1 = __builtin_bit_cast(bf16x8, wv[ab + 346112]);
        const bf16x8 A2 = __builtin_bit_cast(bf16x8, wv[ab + 692224]);
        const int b0 = (((cg * 4) * 338 + ks) * 2 + hi1) * 32 + lo5;
        const bf16x8 B0 = __builtin_bit_cast(bf16x8, zv[b0]);
        const bf16x8 B1 = __builtin_bit_cast(bf16x8, zv[b0 + 21632]);
        const bf16x8 B2 = __builtin_bit_cast(bf16x8, zv[b0 + 43264]);
        const bf16x8 B3 = __builtin_bit_cast(bf16x8, zv[b0 + 64896]);
        acc0 = __builtin_amdgcn_mfma_f32_32x32x16_bf16(A0, B0, acc0, 0, 0, 0);
        acc1 = __builtin_amdgcn_mfma_f32_32x32x16_bf16(A0, B1, acc1, 0, 0, 0);
        acc2 = __builtin_amdgcn_mfma_f32_32x32x16_bf16(A0, B2, acc2, 0, 0, 0);
        acc3 = __builtin_amdgcn_mfma_f32_32x32x16_bf16(A0, B3, acc3, 0, 0, 0);
        acc0 = __builtin_amdgcn_mfma_f32_32x32x16_bf16(A1, B0, acc0, 0, 0, 0);
        acc1 = __builtin_amdgcn_mfma_f32_32x32x16_bf16(A1, B1, acc1, 0, 0, 0);
        acc2 = __builtin_amdgcn_mfma_f32_32x32x16_bf16(A1, B2, acc2, 0, 0, 0);
        acc3 = __builtin_amdgcn_mfma_f32_32x32x16_bf16(A1, B3, acc3, 0, 0, 0);
        acc0 = __builtin_amdgcn_mfma_f32_32x32x16_bf16(A2, B0, acc0, 0, 0, 0);
        acc1 = __builtin_amdgcn_mfma_f32_32x32x16_bf16(A2, B1, acc1, 0, 0, 0);
        acc2 = __builtin_amdgcn_mfma_f32_32x32x16_bf16(A2, B2, acc2, 0, 0, 0);
        acc3 = __builtin_amdgcn_mfma_f32_32x32x16_bf16(A2, B3, acc3, 0, 0, 0);
    }

    float* __restrict__ pp = part + ((size_t)(kc * 512 + nt * 32)) * 1024 + cg * 128 + lo5;
    #pragma unroll
    for (int r = 0; r < 16; ++r) {
        const int row = (r & 3) + 8 * (r >> 2) + 4 * hi1;
        pp[row * 1024]      = acc0[r];
        pp[row * 1024 + 32] = acc1[r];
        pp[row * 1024 + 64] = acc2[r];
        pp[row * 1024 + 96] = acc3[r];
    }
}

// ---------------- K3b: reduce 13 partials + bias + LIF scan over t ----------------
__global__ __launch_bounds__(256) void k3b_lif(
    const float* __restrict__ part,  // [13][512][1024], col = t*32+b
    const float* __restrict__ fb,
    float* __restrict__ za)          // [32t][500][32]
{
    const int idx = blockIdx.x * 256 + threadIdx.x;
    if (idx >= 16000) return;
    const int n = idx >> 5, b = idx & 31;
    const float bias = fb[n];

    float v = 0.f, cu = 0.f;
    for (int t = 0; t < T_STEPS; ++t) {
        float s = 0.f;
        #pragma unroll
        for (int p = 0; p < 13; ++p)
            s += part[(size_t)p * 524288 + n * 1024 + t * 32 + b];
        s += bias;

        const float vd = v + 0.1f * (cu - v);
        const float id = 0.8f * cu;
        const float z = (vd - 1.0f > 0.0f) ? 1.0f : 0.0f;
        v = (z > 0.f) ? 0.f : vd;
        cu = id + s;
        za[(size_t)t * 16000 + idx] = z;
    }
}

// ---------------- K4: readout dots per (c,t) ----------------
__global__ __launch_bounds__(256) void k4_dot(
    const float* __restrict__ za,
    const float* __restrict__ ow,
    float* __restrict__ dota)
{
    const int c = blockIdx.x, t = blockIdx.y;
    const int tid = threadIdx.x;
    const int b = tid & 31, nc = tid >> 5;
    const float* __restrict__ wr = ow + c * 500;
    const float* __restrict__ zt = za + (size_t)t * 16000;

    float acc = 0.f;
    for (int j = 0; j < 63; ++j) {
        const int n = nc * 63 + j;
        if (n < 500) acc = fmaf(zt[n * 32 + b], wr[n], acc);
    }

    __shared__ float red[256];
    red[tid] = acc;
    __syncthreads();
    if (tid < 32) {
        float dot = 0.f;
        #pragma unroll
        for (int q = 0; q < 8; ++q) dot += red[q * 32 + tid];
        dota[((size_t)t * 10 + c) * 32 + tid] = dot;
    }
}

// ---------------- K5: LI scan + output ----------------
__global__ __launch_bounds__(320) void k5_li(
    const float* __restrict__ dota,
    float* __restrict__ outp)
{
    const int tid = threadIdx.x;
    if (tid >= 320) return;
    const int c = tid / 32, b = tid & 31;

    float vo = 0.f, io = 0.f;
    for (int t = 0; t < T_STEPS; ++t) {
        const float vout = vo + 0.1f * (io - vo);
        outp[t * 320 + b * 10 + c] = vout;
        vo = vout;
        io = 0.8f * io + dota[(t * 10 + c) * 32 + b];
    }
}

extern "C" void kernel_launch(void* const* d_in, const int* in_sizes, int n_in,
                              void* d_out, int out_size, void* d_ws, size_t ws_size,
                              hipStream_t stream) {
    const float* x  = (const float*)d_in[0];
    const float* w1 = (const float*)d_in[1];
    const float* b1 = (const float*)d_in[2];
    const float* w2 = (const float*)d_in[3];
    const float* b2 = (const float*)d_in[4];
    const float* fw = (const float*)d_in[5];
    const float* fb = (const float*)d_in[6];
    const float* ow = (const float*)d_in[7];
    float* out = (float*)d_out;
    float* ws = (float*)d_ws;

    size_t off = 0;
    float* zp1a = ws + off; off += 14745600;  // [32t][16*30*30][32b]; dead after k2a
    float* zp2a = ws + off; off += 5537792;   // [32t][5408][32b]
    float* za   = ws + off; off += 512000;
    float* dota = ws + off; off += 10240;
    unsigned short* wsplit = (unsigned short*)(ws + off); off += 19200;
    float* big  = ws + off; off += 22151168;  // union: xT(4.2M)/conv2raw(22.2M)/part(6.8M)
    // ~172 MB total; every region fully written before read.

    float* xT       = big;
    float* conv2raw = big;
    float* part     = big;
    // Overlays in zp1a (dead after k2a): zb (2.77M floats), wf (at +4.19M, 4.16M floats)
    unsigned short* zb = (unsigned short*)zp1a;
    unsigned short* wf = (unsigned short*)(zp1a + 4194304);

    k2w_split<<<50, 256, 0, stream>>>(w2, wsplit);
    k_tr     <<<dim3(64, 32), 256, 0, stream>>>(x, xT);
    k1_conv1 <<<900, 256, 0, stream>>>(xT, w1, b1, zp1a);
    k2a_mfma <<<1352, 256, 0, stream>>>(zp1a, wsplit, conv2raw);
    k2b_lifpool<<<676, 256, 0, stream>>>(conv2raw, b2, zp2a);
    k3w_split<<<676, 256, 0, stream>>>(fw, wf);       // zp1a dead: safe overlay
    zpack    <<<2704, 256, 0, stream>>>(zp2a, zb);
    k3_mfma  <<<416, 256, 0, stream>>>(wf, zb, part);
    k3b_lif  <<<63, 256, 0, stream>>>(part, fb, za);
    k4_dot   <<<dim3(10, 32), 256, 0, stream>>>(za, ow, dota);
    k5_li    <<<1, 320, 0, stream>>>(dota, out);
}

// Round 11
// 258.949 us; speedup vs baseline: 57.6071x; 1.0138x over previous
//
#include <hip/hip_runtime.h>

// SNN: v_dec = v + 0.1*(i - v); i_dec = 0.8*i; spike if v_dec > 1.0
// v' = spike ? 0 : v_dec; i' = i_dec + input.

#define T_STEPS 32

typedef __bf16 bf16x8 __attribute__((ext_vector_type(8)));
typedef float f32x16 __attribute__((ext_vector_type(16)));
typedef int i32x4 __attribute__((ext_vector_type(4)));

// Bijective XCD-chunked block swizzle (m204).
__device__ __forceinline__ int xcd_swz(int orig, int nwg) {
    const int q = nwg >> 3, r = nwg & 7;
    const int xcd = orig & 7, idx = orig >> 3;
    return (xcd < r ? xcd * (q + 1) : r * (q + 1) + (xcd - r) * q) + idx;
}

// ---------------- K0: transpose x [t][b][64][64] -> xT [t][y][x][b] ----------------
__global__ __launch_bounds__(256) void k_tr(
    const float* __restrict__ x, float* __restrict__ xT)
{
    const int y = blockIdx.x, t = blockIdx.y;
    const int tid = threadIdx.x;
    __shared__ float tile[32][65];

    const int lx = tid & 63, bg = tid >> 6;
    #pragma unroll
    for (int p = 0; p < 8; ++p) {
        const int b = bg + p * 4;
        tile[b][lx] = x[((size_t)(t * 32 + b) * 64 + y) * 64 + lx];
    }
    __syncthreads();
    const int wb = tid & 31, xg = tid >> 5;
    #pragma unroll
    for (int p = 0; p < 8; ++p) {
        const int xx = xg + p * 8;
        xT[((size_t)(t * 64 + y) * 64 + xx) * 32 + wb] = tile[wb][xx];
    }
}

// ---------------- K1: conv1 (1->16) + LIF + pool, ALL timesteps ----------------
// grid (900 pos XCD-swizzled, 2 co-halves), block 256 = 32 b x 8 slots (1 co each).
// Spikes stored PACKED bf16-pair u32 in k2a's B-frag layout:
// zp1c_u32[t][cig(2)][py30][px30][pair4][b32], word = ci_even | ci_odd<<16.
__global__ __launch_bounds__(256) void k1_conv1(
    const float* __restrict__ xT,    // [32t,64,64,32b]
    const float* __restrict__ w1,    // [16,1,5,5]
    const float* __restrict__ b1,    // [16]
    unsigned short* __restrict__ zp1c)
{
    const int pos = xcd_swz(blockIdx.x, 900);
    const int bhalf = blockIdx.y;          // = cig
    const int py = pos / 30, px = pos % 30;
    const int y0 = 2 * py, x0 = 2 * px;
    const int tid = threadIdx.x;
    const int b = tid & 31, slot = tid >> 5;
    const int co = bhalf * 8 + slot;

    __shared__ float ws[200];
    for (int i = tid; i < 200; i += 256) ws[i] = w1[bhalf * 200 + i];
    __syncthreads();
    const float bias = b1[co];
    const float* __restrict__ wc = ws + slot * 25;

    float v[4] = {0.f,0.f,0.f,0.f};
    float cu[4] = {0.f,0.f,0.f,0.f};

    // u16 destination index (constant part): [(t*2+cig)*900+pos]*128 + pair*32 + b, x2 + half
    const size_t obase = ((size_t)bhalf * 900 + pos) * 128 + (slot >> 1) * 32 + b;
    const int half = slot & 1;

    for (int t = 0; t < T_STEPS; ++t) {
        float xr[36];
        const float* __restrict__ bt =
            xT + ((size_t)(t * 64 + y0) * 64 + x0) * 32 + b;
        #pragma unroll
        for (int r = 0; r < 6; ++r) {
            const float* __restrict__ pr = bt + r * 2048;
            #pragma unroll
            for (int c = 0; c < 6; ++c) xr[r * 6 + c] = pr[c * 32];
        }

        float acc[4] = {0.f, 0.f, 0.f, 0.f};
        #pragma unroll
        for (int ky = 0; ky < 5; ++ky) {
            #pragma unroll
            for (int kx = 0; kx < 5; ++kx) {
                const float w = wc[ky * 5 + kx];
                acc[0] = fmaf(w, xr[ky * 6 + kx],           acc[0]);
                acc[1] = fmaf(w, xr[ky * 6 + kx + 1],       acc[1]);
                acc[2] = fmaf(w, xr[(ky + 1) * 6 + kx],     acc[2]);
                acc[3] = fmaf(w, xr[(ky + 1) * 6 + kx + 1], acc[3]);
            }
        }

        float zmax = 0.f;
        #pragma unroll
        for (int q = 0; q < 4; ++q) {
            const float inp = acc[q] + bias;
            const float vv = v[q], cur = cu[q];
            const float vd = vv + 0.1f * (cur - vv);
            const float id = 0.8f * cur;
            const float z = (vd - 1.0f > 0.0f) ? 1.0f : 0.0f;
            v[q] = (z > 0.f) ? 0.f : vd;
            cu[q] = id + inp;
            zmax = fmaxf(zmax, z);
        }
        // bf16 of 0.0/1.0 is exact
        zp1c[((size_t)t * 230400 + obase) * 2 + half] =
            (unsigned short)(__float_as_uint(zmax) >> 16);
    }
}

// ---------------- K2w: 3-way bf16 split of conv2 weights ----------------
__global__ __launch_bounds__(256) void k2w_split(
    const float* __restrict__ w2, unsigned short* __restrict__ wsplit)
{
    const int i = blockIdx.x * 256 + threadIdx.x;
    if (i >= 12800) return;
    const int co = i / 400, rest = i % 400;
    const int ci = rest / 25, tap = rest % 25;
    const float w = w2[i];
    const unsigned wb = __float_as_uint(w);
    const unsigned hi = wb & 0xFFFF0000u;
    const float r1 = w - __uint_as_float(hi);
    const unsigned mid = __float_as_uint(r1) & 0xFFFF0000u;
    const float r2 = r1 - __uint_as_float(mid);
    const unsigned lo = __float_as_uint(r2) & 0xFFFF0000u;
    const int base = (tap * 32 + co) * 16 + ci;
    wsplit[base]         = (unsigned short)(hi >> 16);
    wsplit[12800 + base] = (unsigned short)(mid >> 16);
    wsplit[25600 + base] = (unsigned short)(lo >> 16);
}

// ---------------- K2a: conv2 as MFMA GEMM (unfused) ----------------
// B-frags now read pre-packed from zp1c: 4 dword loads per cell, zero packing.
__global__ __launch_bounds__(256, 2) void k2a_mfma(
    const unsigned* __restrict__ zp1c,       // [32t][2cig][30][30][4p][32b] u32
    const unsigned short* __restrict__ wsplit,
    float* __restrict__ raw)                 // [32t][169pg][4q][32co][32b]
{
    __shared__ i32x4 wlds[4800];  // [3sp][25tap][32co][2cig]
    const int tid = threadIdx.x;
    for (int i = tid; i < 4800; i += 256)
        wlds[i] = ((const i32x4*)wsplit)[i];
    __syncthreads();

    const int w = tid >> 6, l = tid & 63;
    const int task = xcd_swz(blockIdx.x, 1352) * 4 + w;
    const int t = task / 169, pg = task % 169;
    const int py = pg / 13, px = pg % 13;
    const int b = l & 31, cig = l >> 5;
    const int abase = (l & 31) * 2 + cig;

    const unsigned* __restrict__ zt =
        zp1c + (size_t)(t * 2 + cig) * 115200 + ((2 * py) * 30 + 2 * px) * 128 + b;

    f32x16 accA, accB, accC, accD;
    #pragma unroll
    for (int r = 0; r < 16; ++r) { accA[r] = 0.f; accB[r] = 0.f; accC[r] = 0.f; accD[r] = 0.f; }

    #pragma unroll
    for (int wy = 0; wy < 6; ++wy) {
        i32x4 bw[6];
        #pragma unroll
        for (int wx = 0; wx < 6; ++wx) {
            const unsigned* __restrict__ c = zt + (wy * 30 + wx) * 128;
            bw[wx][0] = (int)c[0];
            bw[wx][1] = (int)c[32];
            bw[wx][2] = (int)c[64];
            bw[wx][3] = (int)c[96];
        }
        if (wy <= 4) {
            #pragma unroll
            for (int sp = 0; sp < 3; ++sp) {
                #pragma unroll
                for (int kx = 0; kx < 5; ++kx) {
                    const int tap = wy * 5 + kx;
                    const bf16x8 A = __builtin_bit_cast(bf16x8, wlds[(sp * 25 + tap) * 64 + abase]);
                    accA = __builtin_amdgcn_mfma_f32_32x32x16_bf16(
                        A, __builtin_bit_cast(bf16x8, bw[kx]),     accA, 0, 0, 0);
                    accB = __builtin_amdgcn_mfma_f32_32x32x16_bf16(
                        A, __builtin_bit_cast(bf16x8, bw[kx + 1]), accB, 0, 0, 0);
                }
            }
        }
        if (wy >= 1) {
            #pragma unroll
            for (int sp = 0; sp < 3; ++sp) {
                #pragma unroll
                for (int kx = 0; kx < 5; ++kx) {
                    const int tap = (wy - 1) * 5 + kx;
                    const bf16x8 A = __builtin_bit_cast(bf16x8, wlds[(sp * 25 + tap) * 64 + abase]);
                    accC = __builtin_amdgcn_mfma_f32_32x32x16_bf16(
                        A, __builtin_bit_cast(bf16x8, bw[kx]),     accC, 0, 0, 0);
                    accD = __builtin_amdgcn_mfma_f32_32x32x16_bf16(
                        A, __builtin_bit_cast(bf16x8, bw[kx + 1]), accD, 0, 0, 0);
                }
            }
        }
    }

    float* __restrict__ rp = raw + (size_t)(t * 169 + pg) * 4096 + b;
    const int hi = l >> 5;
    #pragma unroll
    for (int r = 0; r < 16; ++r) {
        const int row = (r & 3) + 8 * (r >> 2) + 4 * hi;
        rp[row * 32]        = accA[r];
        rp[1024 + row * 32] = accB[r];
        rp[2048 + row * 32] = accC[r];
        rp[3072 + row * 32] = accD[r];
    }
}

// ---------------- K2b: LIF + pool scan over t ----------------
__global__ __launch_bounds__(256) void k2b_lifpool(
    const float* __restrict__ raw,   // [32t][169pg][4q][32co][32b]
    const float* __restrict__ b2,
    float* __restrict__ zp2a)        // [32t][5408][32b]
{
    const int bid = blockIdx.x;
    const int pg = bid >> 2, cog = bid & 3;
    const int tid = threadIdx.x;
    const int co = cog * 8 + (tid >> 5), b = tid & 31;
    const float bias = b2[co];
    const float* __restrict__ rp = raw + (size_t)pg * 4096 + co * 32 + b;

    float v0=0.f,v1=0.f,v2=0.f,v3=0.f, c0=0.f,c1=0.f,c2=0.f,c3=0.f;
    for (int t = 0; t < T_STEPS; ++t) {
        const float* __restrict__ r = rp + (size_t)t * 692224;
        float zm = 0.f;
        { const float inp = 10.f*(r[0]    + bias); const float vd = v0 + 0.1f*(c0-v0);
          const float z = (vd-1.f>0.f)?1.f:0.f; v0 = (z>0.f)?0.f:vd; c0 = 0.8f*c0 + inp;
          zm = fmaxf(zm, z); }
        { const float inp = 10.f*(r[1024] + bias); const float vd = v1 + 0.1f*(c1-v1);
          const float z = (vd-1.f>0.f)?1.f:0.f; v1 = (z>0.f)?0.f:vd; c1 = 0.8f*c1 + inp;
          zm = fmaxf(zm, z); }
        { const float inp = 10.f*(r[2048] + bias); const float vd = v2 + 0.1f*(c2-v2);
          const float z = (vd-1.f>0.f)?1.f:0.f; v2 = (z>0.f)?0.f:vd; c2 = 0.8f*c2 + inp;
          zm = fmaxf(zm, z); }
        { const float inp = 10.f*(r[3072] + bias); const float vd = v3 + 0.1f*(c3-v3);
          const float z = (vd-1.f>0.f)?1.f:0.f; v3 = (z>0.f)?0.f:vd; c3 = 0.8f*c3 + inp;
          zm = fmaxf(zm, z); }
        zp2a[(size_t)t * 173056 + (co * 169 + pg) * 32 + b] = zm;
    }
}

// ---------------- K3w: 3-way bf16 split of FC weights ----------------
// wf[3sp][16nt][338ks][32n][16k] bf16; rows n>=500 zero-padded.
__global__ __launch_bounds__(256) void k3w_split(
    const float* __restrict__ fw, unsigned short* __restrict__ wf)
{
    const int gid = blockIdx.x * 256 + threadIdx.x;  // 173056 total
    const int l = gid & 31;
    const int ks = (gid >> 5) % 338;
    const int nt = gid / 10816;
    const int n = nt * 32 + l;

    unsigned hipk[8], midpk[8], lopk[8];
    #pragma unroll
    for (int p = 0; p < 8; ++p) {
        unsigned h[2], m[2], o[2];
        #pragma unroll
        for (int e = 0; e < 2; ++e) {
            const float w = (n < 500) ? fw[(size_t)n * 5408 + ks * 16 + 2 * p + e] : 0.f;
            const unsigned wb = __float_as_uint(w);
            const unsigned hi = wb & 0xFFFF0000u;
            const float r1 = w - __uint_as_float(hi);
            const unsigned mid = __float_as_uint(r1) & 0xFFFF0000u;
            const float r2 = r1 - __uint_as_float(mid);
            h[e] = hi >> 16; m[e] = mid >> 16; o[e] = __float_as_uint(r2) >> 16;
        }
        hipk[p]  = h[0] | (h[1] << 16);
        midpk[p] = m[0] | (m[1] << 16);
        lopk[p]  = o[0] | (o[1] << 16);
    }

    i32x4* __restrict__ wv = (i32x4*)wf;
    const int base = (nt * 338 + ks) * 64 + l * 2;  // i32x4 units; sp stride 346112
    i32x4 a, bq;
    a[0]=(int)hipk[0];a[1]=(int)hipk[1];a[2]=(int)hipk[2];a[3]=(int)hipk[3];
    bq[0]=(int)hipk[4];bq[1]=(int)hipk[5];bq[2]=(int)hipk[6];bq[3]=(int)hipk[7];
    wv[base] = a; wv[base + 1] = bq;
    a[0]=(int)midpk[0];a[1]=(int)midpk[1];a[2]=(int)midpk[2];a[3]=(int)midpk[3];
    bq[0]=(int)midpk[4];bq[1]=(int)midpk[5];bq[2]=(int)midpk[6];bq[3]=(int)midpk[7];
    wv[base + 346112] = a; wv[base + 346113] = bq;
    a[0]=(int)lopk[0];a[1]=(int)lopk[1];a[2]=(int)lopk[2];a[3]=(int)lopk[3];
    bq[0]=(int)lopk[4];bq[1]=(int)lopk[5];bq[2]=(int)lopk[6];bq[3]=(int)lopk[7];
    wv[base + 692224] = a; wv[base + 692225] = bq;
}

// ---------------- Zpack: zp2a fp32 -> zb bf16 [32t][338ks][2kh][32b][8k] ----------------
__global__ __launch_bounds__(256) void zpack(
    const float* __restrict__ zp2a, unsigned short* __restrict__ zb)
{
    const int gid = blockIdx.x * 256 + threadIdx.x;  // 692224 total
    const int b = gid & 31;
    const int kh = (gid >> 5) & 1;
    const int rest = gid >> 6;
    const int ks = rest % 338;
    const int t = rest / 338;

    const float* __restrict__ zp = zp2a + (size_t)t * 173056 + (ks * 16 + kh * 8) * 32 + b;
    i32x4 pk;
    #pragma unroll
    for (int p = 0; p < 4; ++p) {
        const unsigned v0 = __float_as_uint(zp[(2 * p) * 32]) >> 16;
        const unsigned v1 = __float_as_uint(zp[(2 * p + 1) * 32]) & 0xFFFF0000u;
        pk[p] = (int)(v0 | v1);
    }
    ((i32x4*)zb)[gid] = pk;
}

// ---------------- K3: FC as MFMA GEMM, no LDS ----------------
__global__ __launch_bounds__(256) void k3_mfma(
    const unsigned short* __restrict__ wf,   // [3][16nt][338ks][32n][16k]
    const unsigned short* __restrict__ zb,   // [32t][338ks][2kh][32b][8k]
    float* __restrict__ part)                // [13][512][1024]
{
    const int wgid = xcd_swz(blockIdx.x, 416);
    const int ntg = wgid / 52, rest = wgid % 52;
    const int kc = rest >> 2, cgg = rest & 3;
    const int tid = threadIdx.x;
    const int w = tid >> 6, l = tid & 63;
    const int nt = ntg * 2 + (w >> 1);
    const int cg = cgg * 2 + (w & 1);
    const int lo5 = l & 31, hi1 = l >> 5;

    const i32x4* __restrict__ wv = (const i32x4*)wf;
    const i32x4* __restrict__ zv = (const i32x4*)zb;

    f32x16 acc0, acc1, acc2, acc3;
    #pragma unroll
    for (int r = 0; r < 16; ++r) { acc0[r]=0.f; acc1[r]=0.f; acc2[r]=0.f; acc3[r]=0.f; }

    const int ks0 = kc * 26;
    #pragma unroll 2
    for (int kk = 0; kk < 26; ++kk) {
        const int ks = ks0 + kk;
        const int ab = (nt * 338 + ks) * 64 + lo5 * 2 + hi1;
        const bf16x8 A0 = __builtin_bit_cast(bf16x8, wv[ab]);
        const bf16x8 A1 = __builtin_bit_cast(bf16x8, wv[ab + 346112]);
        const bf16x8 A2 = __builtin_bit_cast(bf16x8, wv[ab + 692224]);
        const int b0 = (((cg * 4) * 338 + ks) * 2 + hi1) * 32 + lo5;
        const bf16x8 B0 = __builtin_bit_cast(bf16x8, zv[b0]);
        const bf16x8 B1 = __builtin_bit_cast(bf16x8, zv[b0 + 21632]);
        const bf16x8 B2 = __builtin_bit_cast(bf16x8, zv[b0 + 43264]);
        const bf16x8 B3 = __builtin_bit_cast(bf16x8, zv[b0 + 64896]);
        acc0 = __builtin_amdgcn_mfma_f32_32x32x16_bf16(A0, B0, acc0, 0, 0, 0);
        acc1 = __builtin_amdgcn_mfma_f32_32x32x16_bf16(A0, B1, acc1, 0, 0, 0);
        acc2 = __builtin_amdgcn_mfma_f32_32x32x16_bf16(A0, B2, acc2, 0, 0, 0);
        acc3 = __builtin_amdgcn_mfma_f32_32x32x16_bf16(A0, B3, acc3, 0, 0, 0);
        acc0 = __builtin_amdgcn_mfma_f32_32x32x16_bf16(A1, B0, acc0, 0, 0, 0);
        acc1 = __builtin_amdgcn_mfma_f32_32x32x16_bf16(A1, B1, acc1, 0, 0, 0);
        acc2 = __builtin_amdgcn_mfma_f32_32x32x16_bf16(A1, B2, acc2, 0, 0, 0);
        acc3 = __builtin_amdgcn_mfma_f32_32x32x16_bf16(A1, B3, acc3, 0, 0, 0);
        acc0 = __builtin_amdgcn_mfma_f32_32x32x16_bf16(A2, B0, acc0, 0, 0, 0);
        acc1 = __builtin_amdgcn_mfma_f32_32x32x16_bf16(A2, B1, acc1, 0, 0, 0);
        acc2 = __builtin_amdgcn_mfma_f32_32x32x16_bf16(A2, B2, acc2, 0, 0, 0);
        acc3 = __builtin_amdgcn_mfma_f32_32x32x16_bf16(A2, B3, acc3, 0, 0, 0);
    }

    float* __restrict__ pp = part + ((size_t)(kc * 512 + nt * 32)) * 1024 + cg * 128 + lo5;
    #pragma unroll
    for (int r = 0; r < 16; ++r) {
        const int row = (r & 3) + 8 * (r >> 2) + 4 * hi1;
        pp[row * 1024]      = acc0[r];
        pp[row * 1024 + 32] = acc1[r];
        pp[row * 1024 + 64] = acc2[r];
        pp[row * 1024 + 96] = acc3[r];
    }
}

// ---------------- K3b: reduce 13 partials + bias + LIF scan over t ----------------
__global__ __launch_bounds__(256) void k3b_lif(
    const float* __restrict__ part,  // [13][512][1024], col = t*32+b
    const float* __restrict__ fb,
    float* __restrict__ za)          // [32t][500][32]
{
    const int idx = blockIdx.x * 256 + threadIdx.x;
    if (idx >= 16000) return;
    const int n = idx >> 5, b = idx & 31;
    const float bias = fb[n];

    float v = 0.f, cu = 0.f;
    for (int t = 0; t < T_STEPS; ++t) {
        float s = 0.f;
        #pragma unroll
        for (int p = 0; p < 13; ++p)
            s += part[(size_t)p * 524288 + n * 1024 + t * 32 + b];
        s += bias;

        const float vd = v + 0.1f * (cu - v);
        const float id = 0.8f * cu;
        const float z = (vd - 1.0f > 0.0f) ? 1.0f : 0.0f;
        v = (z > 0.f) ? 0.f : vd;
        cu = id + s;
        za[(size_t)t * 16000 + idx] = z;
    }
}

// ---------------- K4: readout dots per (c,t) ----------------
__global__ __launch_bounds__(256) void k4_dot(
    const float* __restrict__ za,
    const float* __restrict__ ow,
    float* __restrict__ dota)
{
    const int c = blockIdx.x, t = blockIdx.y;
    const int tid = threadIdx.x;
    const int b = tid & 31, nc = tid >> 5;
    const float* __restrict__ wr = ow + c * 500;
    const float* __restrict__ zt = za + (size_t)t * 16000;

    float acc = 0.f;
    for (int j = 0; j < 63; ++j) {
        const int n = nc * 63 + j;
        if (n < 500) acc = fmaf(zt[n * 32 + b], wr[n], acc);
    }

    __shared__ float red[256];
    red[tid] = acc;
    __syncthreads();
    if (tid < 32) {
        float dot = 0.f;
        #pragma unroll
        for (int q = 0; q < 8; ++q) dot += red[q * 32 + tid];
        dota[((size_t)t * 10 + c) * 32 + tid] = dot;
    }
}

// ---------------- K5: LI scan + output ----------------
__global__ __launch_bounds__(320) void k5_li(
    const float* __restrict__ dota,
    float* __restrict__ outp)
{
    const int tid = threadIdx.x;
    if (tid >= 320) return;
    const int c = tid / 32, b = tid & 31;

    float vo = 0.f, io = 0.f;
    for (int t = 0; t < T_STEPS; ++t) {
        const float vout = vo + 0.1f * (io - vo);
        outp[t * 320 + b * 10 + c] = vout;
        vo = vout;
        io = 0.8f * io + dota[(t * 10 + c) * 32 + b];
    }
}

extern "C" void kernel_launch(void* const* d_in, const int* in_sizes, int n_in,
                              void* d_out, int out_size, void* d_ws, size_t ws_size,
                              hipStream_t stream) {
    const float* x  = (const float*)d_in[0];
    const float* w1 = (const float*)d_in[1];
    const float* b1 = (const float*)d_in[2];
    const float* w2 = (const float*)d_in[3];
    const float* b2 = (const float*)d_in[4];
    const float* fw = (const float*)d_in[5];
    const float* fb = (const float*)d_in[6];
    const float* ow = (const float*)d_in[7];
    float* out = (float*)d_out;
    float* ws = (float*)d_ws;

    size_t off = 0;
    float* zp1a = ws + off; off += 14745600;  // zp1c (29.5MB u32-packed) lives here; dead after k2a
    float* zp2a = ws + off; off += 5537792;   // [32t][5408][32b]
    float* za   = ws + off; off += 512000;
    float* dota = ws + off; off += 10240;
    unsigned short* wsplit = (unsigned short*)(ws + off); off += 19200;
    float* big  = ws + off; off += 22151168;  // union: xT(4.2M)/conv2raw(22.2M)/part(6.8M)
    // ~172 MB total; every region fully written before read.

    float* xT       = big;
    float* conv2raw = big;
    float* part     = big;
    unsigned short* zp1c = (unsigned short*)zp1a;   // [32t][2][900][4][32] u32 packed
    // Overlays in zp1a region (dead after k2a): zb, wf
    unsigned short* zb = (unsigned short*)zp1a;
    unsigned short* wf = (unsigned short*)(zp1a + 4194304);

    k2w_split<<<50, 256, 0, stream>>>(w2, wsplit);
    k_tr     <<<dim3(64, 32), 256, 0, stream>>>(x, xT);
    k1_conv1 <<<dim3(900, 2), 256, 0, stream>>>(xT, w1, b1, zp1c);
    k2a_mfma <<<1352, 256, 0, stream>>>((const unsigned*)zp1c, wsplit, conv2raw);
    k2b_lifpool<<<676, 256, 0, stream>>>(conv2raw, b2, zp2a);
    k3w_split<<<676, 256, 0, stream>>>(fw, wf);       // zp1c dead: safe overlay
    zpack    <<<2704, 256, 0, stream>>>(zp2a, zb);
    k3_mfma  <<<416, 256, 0, stream>>>(wf, zb, part);
    k3b_lif  <<<63, 256, 0, stream>>>(part, fb, za);
    k4_dot   <<<dim3(10, 32), 256, 0, stream>>>(za, ow, dota);
    k5_li    <<<1, 320, 0, stream>>>(dota, out);
}

// Round 12
// 236.180 us; speedup vs baseline: 63.1609x; 1.0964x over previous
//
#include <hip/hip_runtime.h>

// SNN: v_dec = v + 0.1*(i - v); i_dec = 0.8*i; spike if v_dec > 1.0
// v' = spike ? 0 : v_dec; i' = i_dec + input.

#define T_STEPS 32

typedef __bf16 bf16x8 __attribute__((ext_vector_type(8)));
typedef float f32x16 __attribute__((ext_vector_type(16)));
typedef int i32x4 __attribute__((ext_vector_type(4)));

// Bijective XCD-chunked block swizzle (m204).
__device__ __forceinline__ int xcd_swz(int orig, int nwg) {
    const int q = nwg >> 3, r = nwg & 7;
    const int xcd = orig & 7, idx = orig >> 3;
    return (xcd < r ? xcd * (q + 1) : r * (q + 1) + (xcd - r) * q) + idx;
}

// ---------------- K0: transpose x [t][b][64][64] -> xT [t][y][x][b] ----------------
__global__ __launch_bounds__(256) void k_tr(
    const float* __restrict__ x, float* __restrict__ xT)
{
    const int y = blockIdx.x, t = blockIdx.y;
    const int tid = threadIdx.x;
    __shared__ float tile[32][65];

    const int lx = tid & 63, bg = tid >> 6;
    #pragma unroll
    for (int p = 0; p < 8; ++p) {
        const int b = bg + p * 4;
        tile[b][lx] = x[((size_t)(t * 32 + b) * 64 + y) * 64 + lx];
    }
    __syncthreads();
    const int wb = tid & 31, xg = tid >> 5;
    #pragma unroll
    for (int p = 0; p < 8; ++p) {
        const int xx = xg + p * 8;
        xT[((size_t)(t * 64 + y) * 64 + xx) * 32 + wb] = tile[wb][xx];
    }
}

// ---------------- K1: conv1 (1->16) + LIF + pool, ALL timesteps ----------------
// grid 900 (pos XCD-swizzled), block 256 = 32 b x 8 slots (2 co per slot).
// Window staged in LDS ONCE per block per t (288 float4 loads) instead of each
// thread loading 36 scalars (8x VMEM redundancy was the R10/R11 wall).
// Output: packed bf16-pair u32 in k2a's B-frag layout.
__global__ __launch_bounds__(256) void k1_conv1(
    const float* __restrict__ xT,    // [32t,64,64,32b]
    const float* __restrict__ w1,    // [16,1,5,5]
    const float* __restrict__ b1,    // [16]
    unsigned short* __restrict__ zp1c)
{
    const int pos = xcd_swz(blockIdx.x, 900);
    const int py = pos / 30, px = pos % 30;
    const int y0 = 2 * py, x0 = 2 * px;
    const int tid = threadIdx.x;
    const int b = tid & 31, slot = tid >> 5;

    __shared__ float ws[400];
    __shared__ float win[1152];      // [6r][6c][32b]
    for (int i = tid; i < 400; i += 256) ws[i] = w1[i];
    const float bias0 = b1[slot], bias1 = b1[slot + 8];
    const float* __restrict__ wc0 = ws + slot * 25;
    const float* __restrict__ wc1 = ws + (slot + 8) * 25;

    float v[2][4] = {{0.f,0.f,0.f,0.f},{0.f,0.f,0.f,0.f}};
    float cu[2][4] = {{0.f,0.f,0.f,0.f},{0.f,0.f,0.f,0.f}};

    // u16 output index pieces: idx = t*460800 + cig*230400 + pos*256 + (slot>>1)*64 + b*2 + (slot&1)
    const size_t obase = (size_t)pos * 256 + (slot >> 1) * 64 + b * 2 + (slot & 1);

    for (int t = 0; t < T_STEPS; ++t) {
        __syncthreads();  // win consumers of t-1 done (and ws ready at t=0)
        // stage 6 rows x 192 contiguous floats = 288 float4
        {
            const float4* __restrict__ src0 =
                (const float4*)(xT + ((size_t)(t * 64 + y0) * 64 + x0) * 32);
            float4* __restrict__ dst = (float4*)win;
            for (int i = tid; i < 288; i += 256) {
                const int r = i / 48, j = i - r * 48;
                dst[r * 48 + j] = src0[r * 512 + j];   // row stride 64*32/4 = 512 float4
            }
        }
        __syncthreads();

        float xr[36];
        #pragma unroll
        for (int rc = 0; rc < 36; ++rc) xr[rc] = win[rc * 32 + b];

        float acc0[4] = {0.f, 0.f, 0.f, 0.f};
        float acc1[4] = {0.f, 0.f, 0.f, 0.f};
        #pragma unroll
        for (int ky = 0; ky < 5; ++ky) {
            #pragma unroll
            for (int kx = 0; kx < 5; ++kx) {
                const float w0 = wc0[ky * 5 + kx];
                const float w1v = wc1[ky * 5 + kx];
                const float e00 = xr[ky * 6 + kx];
                const float e01 = xr[ky * 6 + kx + 1];
                const float e10 = xr[(ky + 1) * 6 + kx];
                const float e11 = xr[(ky + 1) * 6 + kx + 1];
                acc0[0] = fmaf(w0, e00, acc0[0]);
                acc0[1] = fmaf(w0, e01, acc0[1]);
                acc0[2] = fmaf(w0, e10, acc0[2]);
                acc0[3] = fmaf(w0, e11, acc0[3]);
                acc1[0] = fmaf(w1v, e00, acc1[0]);
                acc1[1] = fmaf(w1v, e01, acc1[1]);
                acc1[2] = fmaf(w1v, e10, acc1[2]);
                acc1[3] = fmaf(w1v, e11, acc1[3]);
            }
        }

        #pragma unroll
        for (int half = 0; half < 2; ++half) {
            const float* acc = half ? acc1 : acc0;
            const float bias = half ? bias1 : bias0;
            float zmax = 0.f;
            #pragma unroll
            for (int q = 0; q < 4; ++q) {
                const float inp = acc[q] + bias;
                const float vv = v[half][q], cur = cu[half][q];
                const float vd = vv + 0.1f * (cur - vv);
                const float id = 0.8f * cur;
                const float z = (vd - 1.0f > 0.0f) ? 1.0f : 0.0f;
                v[half][q] = (z > 0.f) ? 0.f : vd;
                cu[half][q] = id + inp;
                zmax = fmaxf(zmax, z);
            }
            // bf16 of 0.0/1.0 is exact
            zp1c[(size_t)t * 460800 + (size_t)half * 230400 + obase] =
                (unsigned short)(__float_as_uint(zmax) >> 16);
        }
    }
}

// ---------------- K2w: 3-way bf16 split of conv2 weights ----------------
__global__ __launch_bounds__(256) void k2w_split(
    const float* __restrict__ w2, unsigned short* __restrict__ wsplit)
{
    const int i = blockIdx.x * 256 + threadIdx.x;
    if (i >= 12800) return;
    const int co = i / 400, rest = i % 400;
    const int ci = rest / 25, tap = rest % 25;
    const float w = w2[i];
    const unsigned wb = __float_as_uint(w);
    const unsigned hi = wb & 0xFFFF0000u;
    const float r1 = w - __uint_as_float(hi);
    const unsigned mid = __float_as_uint(r1) & 0xFFFF0000u;
    const float r2 = r1 - __uint_as_float(mid);
    const unsigned lo = __float_as_uint(r2) & 0xFFFF0000u;
    const int base = (tap * 32 + co) * 16 + ci;
    wsplit[base]         = (unsigned short)(hi >> 16);
    wsplit[12800 + base] = (unsigned short)(mid >> 16);
    wsplit[25600 + base] = (unsigned short)(lo >> 16);
}

// ---------------- K2a: conv2 as MFMA GEMM (unfused) ----------------
__global__ __launch_bounds__(256, 2) void k2a_mfma(
    const unsigned* __restrict__ zp1c,       // [32t][2cig][30][30][4p][32b] u32
    const unsigned short* __restrict__ wsplit,
    float* __restrict__ raw)                 // [32t][169pg][4q][32co][32b]
{
    __shared__ i32x4 wlds[4800];  // [3sp][25tap][32co][2cig]
    const int tid = threadIdx.x;
    for (int i = tid; i < 4800; i += 256)
        wlds[i] = ((const i32x4*)wsplit)[i];
    __syncthreads();

    const int w = tid >> 6, l = tid & 63;
    const int task = xcd_swz(blockIdx.x, 1352) * 4 + w;
    const int t = task / 169, pg = task % 169;
    const int py = pg / 13, px = pg % 13;
    const int b = l & 31, cig = l >> 5;
    const int abase = (l & 31) * 2 + cig;

    const unsigned* __restrict__ zt =
        zp1c + (size_t)(t * 2 + cig) * 115200 + ((2 * py) * 30 + 2 * px) * 128 + b;

    f32x16 accA, accB, accC, accD;
    #pragma unroll
    for (int r = 0; r < 16; ++r) { accA[r] = 0.f; accB[r] = 0.f; accC[r] = 0.f; accD[r] = 0.f; }

    #pragma unroll
    for (int wy = 0; wy < 6; ++wy) {
        i32x4 bw[6];
        #pragma unroll
        for (int wx = 0; wx < 6; ++wx) {
            const unsigned* __restrict__ c = zt + (wy * 30 + wx) * 128;
            bw[wx][0] = (int)c[0];
            bw[wx][1] = (int)c[32];
            bw[wx][2] = (int)c[64];
            bw[wx][3] = (int)c[96];
        }
        if (wy <= 4) {
            #pragma unroll
            for (int sp = 0; sp < 3; ++sp) {
                #pragma unroll
                for (int kx = 0; kx < 5; ++kx) {
                    const int tap = wy * 5 + kx;
                    const bf16x8 A = __builtin_bit_cast(bf16x8, wlds[(sp * 25 + tap) * 64 + abase]);
                    accA = __builtin_amdgcn_mfma_f32_32x32x16_bf16(
                        A, __builtin_bit_cast(bf16x8, bw[kx]),     accA, 0, 0, 0);
                    accB = __builtin_amdgcn_mfma_f32_32x32x16_bf16(
                        A, __builtin_bit_cast(bf16x8, bw[kx + 1]), accB, 0, 0, 0);
                }
            }
        }
        if (wy >= 1) {
            #pragma unroll
            for (int sp = 0; sp < 3; ++sp) {
                #pragma unroll
                for (int kx = 0; kx < 5; ++kx) {
                    const int tap = (wy - 1) * 5 + kx;
                    const bf16x8 A = __builtin_bit_cast(bf16x8, wlds[(sp * 25 + tap) * 64 + abase]);
                    accC = __builtin_amdgcn_mfma_f32_32x32x16_bf16(
                        A, __builtin_bit_cast(bf16x8, bw[kx]),     accC, 0, 0, 0);
                    accD = __builtin_amdgcn_mfma_f32_32x32x16_bf16(
                        A, __builtin_bit_cast(bf16x8, bw[kx + 1]), accD, 0, 0, 0);
                }
            }
        }
    }

    float* __restrict__ rp = raw + (size_t)(t * 169 + pg) * 4096 + b;
    const int hi = l >> 5;
    #pragma unroll
    for (int r = 0; r < 16; ++r) {
        const int row = (r & 3) + 8 * (r >> 2) + 4 * hi;
        rp[row * 32]        = accA[r];
        rp[1024 + row * 32] = accB[r];
        rp[2048 + row * 32] = accC[r];
        rp[3072 + row * 32] = accD[r];
    }
}

// ---------------- K2b: LIF + pool scan over t ----------------
__global__ __launch_bounds__(256) void k2b_lifpool(
    const float* __restrict__ raw,   // [32t][169pg][4q][32co][32b]
    const float* __restrict__ b2,
    float* __restrict__ zp2a)        // [32t][5408][32b]
{
    const int bid = blockIdx.x;
    const int pg = bid >> 2, cog = bid & 3;
    const int tid = threadIdx.x;
    const int co = cog * 8 + (tid >> 5), b = tid & 31;
    const float bias = b2[co];
    const float* __restrict__ rp = raw + (size_t)pg * 4096 + co * 32 + b;

    float v0=0.f,v1=0.f,v2=0.f,v3=0.f, c0=0.f,c1=0.f,c2=0.f,c3=0.f;
    for (int t = 0; t < T_STEPS; ++t) {
        const float* __restrict__ r = rp + (size_t)t * 692224;
        float zm = 0.f;
        { const float inp = 10.f*(r[0]    + bias); const float vd = v0 + 0.1f*(c0-v0);
          const float z = (vd-1.f>0.f)?1.f:0.f; v0 = (z>0.f)?0.f:vd; c0 = 0.8f*c0 + inp;
          zm = fmaxf(zm, z); }
        { const float inp = 10.f*(r[1024] + bias); const float vd = v1 + 0.1f*(c1-v1);
          const float z = (vd-1.f>0.f)?1.f:0.f; v1 = (z>0.f)?0.f:vd; c1 = 0.8f*c1 + inp;
          zm = fmaxf(zm, z); }
        { const float inp = 10.f*(r[2048] + bias); const float vd = v2 + 0.1f*(c2-v2);
          const float z = (vd-1.f>0.f)?1.f:0.f; v2 = (z>0.f)?0.f:vd; c2 = 0.8f*c2 + inp;
          zm = fmaxf(zm, z); }
        { const float inp = 10.f*(r[3072] + bias); const float vd = v3 + 0.1f*(c3-v3);
          const float z = (vd-1.f>0.f)?1.f:0.f; v3 = (z>0.f)?0.f:vd; c3 = 0.8f*c3 + inp;
          zm = fmaxf(zm, z); }
        zp2a[(size_t)t * 173056 + (co * 169 + pg) * 32 + b] = zm;
    }
}

// ---------------- K3w: 3-way bf16 split of FC weights ----------------
// wf[3sp][16nt][338ks][32n][16k] bf16; rows n>=500 zero-padded.
__global__ __launch_bounds__(256) void k3w_split(
    const float* __restrict__ fw, unsigned short* __restrict__ wf)
{
    const int gid = blockIdx.x * 256 + threadIdx.x;  // 173056 total
    const int l = gid & 31;
    const int ks = (gid >> 5) % 338;
    const int nt = gid / 10816;
    const int n = nt * 32 + l;

    unsigned hipk[8], midpk[8], lopk[8];
    #pragma unroll
    for (int p = 0; p < 8; ++p) {
        unsigned h[2], m[2], o[2];
        #pragma unroll
        for (int e = 0; e < 2; ++e) {
            const float w = (n < 500) ? fw[(size_t)n * 5408 + ks * 16 + 2 * p + e] : 0.f;
            const unsigned wb = __float_as_uint(w);
            const unsigned hi = wb & 0xFFFF0000u;
            const float r1 = w - __uint_as_float(hi);
            const unsigned mid = __float_as_uint(r1) & 0xFFFF0000u;
            const float r2 = r1 - __uint_as_float(mid);
            h[e] = hi >> 16; m[e] = mid >> 16; o[e] = __float_as_uint(r2) >> 16;
        }
        hipk[p]  = h[0] | (h[1] << 16);
        midpk[p] = m[0] | (m[1] << 16);
        lopk[p]  = o[0] | (o[1] << 16);
    }

    i32x4* __restrict__ wv = (i32x4*)wf;
    const int base = (nt * 338 + ks) * 64 + l * 2;  // i32x4 units; sp stride 346112
    i32x4 a, bq;
    a[0]=(int)hipk[0];a[1]=(int)hipk[1];a[2]=(int)hipk[2];a[3]=(int)hipk[3];
    bq[0]=(int)hipk[4];bq[1]=(int)hipk[5];bq[2]=(int)hipk[6];bq[3]=(int)hipk[7];
    wv[base] = a; wv[base + 1] = bq;
    a[0]=(int)midpk[0];a[1]=(int)midpk[1];a[2]=(int)midpk[2];a[3]=(int)midpk[3];
    bq[0]=(int)midpk[4];bq[1]=(int)midpk[5];bq[2]=(int)midpk[6];bq[3]=(int)midpk[7];
    wv[base + 346112] = a; wv[base + 346113] = bq;
    a[0]=(int)lopk[0];a[1]=(int)lopk[1];a[2]=(int)lopk[2];a[3]=(int)lopk[3];
    bq[0]=(int)lopk[4];bq[1]=(int)lopk[5];bq[2]=(int)lopk[6];bq[3]=(int)lopk[7];
    wv[base + 692224] = a; wv[base + 692225] = bq;
}

// ---------------- Zpack: zp2a fp32 -> zb bf16 [32t][338ks][2kh][32b][8k] ----------------
__global__ __launch_bounds__(256) void zpack(
    const float* __restrict__ zp2a, unsigned short* __restrict__ zb)
{
    const int gid = blockIdx.x * 256 + threadIdx.x;  // 692224 total
    const int b = gid & 31;
    const int kh = (gid >> 5) & 1;
    const int rest = gid >> 6;
    const int ks = rest % 338;
    const int t = rest / 338;

    const float* __restrict__ zp = zp2a + (size_t)t * 173056 + (ks * 16 + kh * 8) * 32 + b;
    i32x4 pk;
    #pragma unroll
    for (int p = 0; p < 4; ++p) {
        const unsigned v0 = __float_as_uint(zp[(2 * p) * 32]) >> 16;
        const unsigned v1 = __float_as_uint(zp[(2 * p + 1) * 32]) & 0xFFFF0000u;
        pk[p] = (int)(v0 | v1);
    }
    ((i32x4*)zb)[gid] = pk;
}

// ---------------- K3: FC as MFMA GEMM, no LDS ----------------
__global__ __launch_bounds__(256) void k3_mfma(
    const unsigned short* __restrict__ wf,   // [3][16nt][338ks][32n][16k]
    const unsigned short* __restrict__ zb,   // [32t][338ks][2kh][32b][8k]
    float* __restrict__ part)                // [13][512][1024]
{
    const int wgid = xcd_swz(blockIdx.x, 416);
    const int ntg = wgid / 52, rest = wgid % 52;
    const int kc = rest >> 2, cgg = rest & 3;
    const int tid = threadIdx.x;
    const int w = tid >> 6, l = tid & 63;
    const int nt = ntg * 2 + (w >> 1);
    const int cg = cgg * 2 + (w & 1);
    const int lo5 = l & 31, hi1 = l >> 5;

    const i32x4* __restrict__ wv = (const i32x4*)wf;
    const i32x4* __restrict__ zv = (const i32x4*)zb;

    f32x16 acc0, acc1, acc2, acc3;
    #pragma unroll
    for (int r = 0; r < 16; ++r) { acc0[r]=0.f; acc1[r]=0.f; acc2[r]=0.f; acc3[r]=0.f; }

    const int ks0 = kc * 26;
    #pragma unroll 2
    for (int kk = 0; kk < 26; ++kk) {
        const int ks = ks0 + kk;
        const int ab = (nt * 338 + ks) * 64 + lo5 * 2 + hi1;
        const bf16x8 A0 = __builtin_bit_cast(bf16x8, wv[ab]);
        const bf16x8 A1 = __builtin_bit_cast(bf16x8, wv[ab + 346112]);
        const bf16x8 A2 = __builtin_bit_cast(bf16x8, wv[ab + 692224]);
        const int b0 = (((cg * 4) * 338 + ks) * 2 + hi1) * 32 + lo5;
        const bf16x8 B0 = __builtin_bit_cast(bf16x8, zv[b0]);
        const bf16x8 B1 = __builtin_bit_cast(bf16x8, zv[b0 + 21632]);
        const bf16x8 B2 = __builtin_bit_cast(bf16x8, zv[b0 + 43264]);
        const bf16x8 B3 = __builtin_bit_cast(bf16x8, zv[b0 + 64896]);
        acc0 = __builtin_amdgcn_mfma_f32_32x32x16_bf16(A0, B0, acc0, 0, 0, 0);
        acc1 = __builtin_amdgcn_mfma_f32_32x32x16_bf16(A0, B1, acc1, 0, 0, 0);
        acc2 = __builtin_amdgcn_mfma_f32_32x32x16_bf16(A0, B2, acc2, 0, 0, 0);
        acc3 = __builtin_amdgcn_mfma_f32_32x32x16_bf16(A0, B3, acc3, 0, 0, 0);
        acc0 = __builtin_amdgcn_mfma_f32_32x32x16_bf16(A1, B0, acc0, 0, 0, 0);
        acc1 = __builtin_amdgcn_mfma_f32_32x32x16_bf16(A1, B1, acc1, 0, 0, 0);
        acc2 = __builtin_amdgcn_mfma_f32_32x32x16_bf16(A1, B2, acc2, 0, 0, 0);
        acc3 = __builtin_amdgcn_mfma_f32_32x32x16_bf16(A1, B3, acc3, 0, 0, 0);
        acc0 = __builtin_amdgcn_mfma_f32_32x32x16_bf16(A2, B0, acc0, 0, 0, 0);
        acc1 = __builtin_amdgcn_mfma_f32_32x32x16_bf16(A2, B1, acc1, 0, 0, 0);
        acc2 = __builtin_amdgcn_mfma_f32_32x32x16_bf16(A2, B2, acc2, 0, 0, 0);
        acc3 = __builtin_amdgcn_mfma_f32_32x32x16_bf16(A2, B3, acc3, 0, 0, 0);
    }

    float* __restrict__ pp = part + ((size_t)(kc * 512 + nt * 32)) * 1024 + cg * 128 + lo5;
    #pragma unroll
    for (int r = 0; r < 16; ++r) {
        const int row = (r & 3) + 8 * (r >> 2) + 4 * hi1;
        pp[row * 1024]      = acc0[r];
        pp[row * 1024 + 32] = acc1[r];
        pp[row * 1024 + 64] = acc2[r];
        pp[row * 1024 + 96] = acc3[r];
    }
}

// ---------------- K3b: reduce 13 partials + bias + LIF scan over t ----------------
__global__ __launch_bounds__(256) void k3b_lif(
    const float* __restrict__ part,  // [13][512][1024], col = t*32+b
    const float* __restrict__ fb,
    float* __restrict__ za)          // [32t][500][32]
{
    const int idx = blockIdx.x * 256 + threadIdx.x;
    if (idx >= 16000) return;
    const int n = idx >> 5, b = idx & 31;
    const float bias = fb[n];

    float v = 0.f, cu = 0.f;
    for (int t = 0; t < T_STEPS; ++t) {
        float s = 0.f;
        #pragma unroll
        for (int p = 0; p < 13; ++p)
            s += part[(size_t)p * 524288 + n * 1024 + t * 32 + b];
        s += bias;

        const float vd = v + 0.1f * (cu - v);
        const float id = 0.8f * cu;
        const float z = (vd - 1.0f > 0.0f) ? 1.0f : 0.0f;
        v = (z > 0.f) ? 0.f : vd;
        cu = id + s;
        za[(size_t)t * 16000 + idx] = z;
    }
}

// ---------------- K4: readout dots per (c,t) ----------------
__global__ __launch_bounds__(256) void k4_dot(
    const float* __restrict__ za,
    const float* __restrict__ ow,
    float* __restrict__ dota)
{
    const int c = blockIdx.x, t = blockIdx.y;
    const int tid = threadIdx.x;
    const int b = tid & 31, nc = tid >> 5;
    const float* __restrict__ wr = ow + c * 500;
    const float* __restrict__ zt = za + (size_t)t * 16000;

    float acc = 0.f;
    for (int j = 0; j < 63; ++j) {
        const int n = nc * 63 + j;
        if (n < 500) acc = fmaf(zt[n * 32 + b], wr[n], acc);
    }

    __shared__ float red[256];
    red[tid] = acc;
    __syncthreads();
    if (tid < 32) {
        float dot = 0.f;
        #pragma unroll
        for (int q = 0; q < 8; ++q) dot += red[q * 32 + tid];
        dota[((size_t)t * 10 + c) * 32 + tid] = dot;
    }
}

// ---------------- K5: LI scan + output ----------------
__global__ __launch_bounds__(320) void k5_li(
    const float* __restrict__ dota,
    float* __restrict__ outp)
{
    const int tid = threadIdx.x;
    if (tid >= 320) return;
    const int c = tid / 32, b = tid & 31;

    float vo = 0.f, io = 0.f;
    for (int t = 0; t < T_STEPS; ++t) {
        const float vout = vo + 0.1f * (io - vo);
        outp[t * 320 + b * 10 + c] = vout;
        vo = vout;
        io = 0.8f * io + dota[(t * 10 + c) * 32 + b];
    }
}

extern "C" void kernel_launch(void* const* d_in, const int* in_sizes, int n_in,
                              void* d_out, int out_size, void* d_ws, size_t ws_size,
                              hipStream_t stream) {
    const float* x  = (const float*)d_in[0];
    const float* w1 = (const float*)d_in[1];
    const float* b1 = (const float*)d_in[2];
    const float* w2 = (const float*)d_in[3];
    const float* b2 = (const float*)d_in[4];
    const float* fw = (const float*)d_in[5];
    const float* fb = (const float*)d_in[6];
    const float* ow = (const float*)d_in[7];
    float* out = (float*)d_out;
    float* ws = (float*)d_ws;

    size_t off = 0;
    float* zp1a = ws + off; off += 14745600;  // zp1c packed lives here; dead after k2a
    float* zp2a = ws + off; off += 5537792;   // [32t][5408][32b]
    float* za   = ws + off; off += 512000;
    float* dota = ws + off; off += 10240;
    unsigned short* wsplit = (unsigned short*)(ws + off); off += 19200;
    float* big  = ws + off; off += 22151168;  // union: xT(4.2M)/conv2raw(22.2M)/part(6.8M)
    // ~172 MB total; every region fully written before read.

    float* xT       = big;
    float* conv2raw = big;
    float* part     = big;
    unsigned short* zp1c = (unsigned short*)zp1a;   // [32t][2][900][4][32] u32 packed
    unsigned short* zb = (unsigned short*)zp1a;     // overlay, zp1c dead after k2a
    unsigned short* wf = (unsigned short*)(zp1a + 4194304);

    k2w_split<<<50, 256, 0, stream>>>(w2, wsplit);
    k_tr     <<<dim3(64, 32), 256, 0, stream>>>(x, xT);
    k1_conv1 <<<900, 256, 0, stream>>>(xT, w1, b1, zp1c);
    k2a_mfma <<<1352, 256, 0, stream>>>((const unsigned*)zp1c, wsplit, conv2raw);
    k2b_lifpool<<<676, 256, 0, stream>>>(conv2raw, b2, zp2a);
    k3w_split<<<676, 256, 0, stream>>>(fw, wf);       // zp1c dead: safe overlay
    zpack    <<<2704, 256, 0, stream>>>(zp2a, zb);
    k3_mfma  <<<416, 256, 0, stream>>>(wf, zb, part);
    k3b_lif  <<<63, 256, 0, stream>>>(part, fb, za);
    k4_dot   <<<dim3(10, 32), 256, 0, stream>>>(za, ow, dota);
    k5_li    <<<1, 320, 0, stream>>>(dota, out);
}